// Round 1
// baseline (1660.253 us; speedup 1.0000x reference)
//
#include <hip/hip_runtime.h>
#include <hip/hip_bf16.h>
#include <math.h>

#define DM 1024
#define NHEAD 16
#define HD 64
#define ROPE_D 32
#define KVC 256
#define QC 384
#define KVW 288          // KVC + ROPE
#define NSEQ 4
#define SPS 256
#define SEQ 1025         // NSEQ*SPS + 1
#define BATCH 2
#define NH2 32           // NHEAD*2
#define QKD 48           // HD/2 + ROPE/2
#define KSCALE (1.0f/48.0f)
#define EPS_RMS 1.1920929e-07f
#define EPS_HEAD 1e-05f
#define LAMBDA_INIT 0.2f
#define RT_PER 257       // ceil(SEQ/4)

// ---------------------------------------------------------------------------
// Generic tiled fp32 GEMM: C[M,N] = A[M,K] @ B[K,N], row-major, arbitrary ld.
// 128x64 block tile, 16 K-tile, 8x4 microtile per thread (256 threads).
// ---------------------------------------------------------------------------
__global__ __launch_bounds__(256) void gemm_f32(
    const float* __restrict__ A, const float* __restrict__ B,
    float* __restrict__ C, int M, int N, int K, int ldA, int ldB, int ldC)
{
    __shared__ float As[16][132];
    __shared__ float Bs[16][68];
    int bm = blockIdx.y * 128, bn = blockIdx.x * 64;
    int tid = threadIdx.x;
    int ty = tid >> 4, tx = tid & 15;
    int row0 = ty * 8, col0 = tx * 4;
    float acc[8][4] = {};
    for (int k0 = 0; k0 < K; k0 += 16) {
        for (int i = tid; i < 128 * 16; i += 256) {
            int rr = i >> 4, kk = i & 15;
            int gr = bm + rr;
            As[kk][rr] = (gr < M) ? A[(size_t)gr * ldA + k0 + kk] : 0.f;
        }
        for (int i = tid; i < 16 * 64; i += 256) {
            int kk = i >> 6, cc = i & 63;
            int gc = bn + cc;
            Bs[kk][cc] = (gc < N) ? B[(size_t)(k0 + kk) * ldB + gc] : 0.f;
        }
        __syncthreads();
#pragma unroll
        for (int kk = 0; kk < 16; ++kk) {
            float bv[4], av[8];
#pragma unroll
            for (int j = 0; j < 4; ++j) bv[j] = Bs[kk][col0 + j];
#pragma unroll
            for (int i = 0; i < 8; ++i) av[i] = As[kk][row0 + i];
#pragma unroll
            for (int i = 0; i < 8; ++i)
#pragma unroll
                for (int j = 0; j < 4; ++j)
                    acc[i][j] = fmaf(av[i], bv[j], acc[i][j]);
        }
        __syncthreads();
    }
    for (int i = 0; i < 8; ++i) {
        int gr = bm + row0 + i;
        if (gr >= M) break;
        for (int j = 0; j < 4; ++j) {
            int gc = bn + col0 + j;
            if (gc < N) C[(size_t)gr * ldC + gc] = acc[i][j];
        }
    }
}

// ---------------------------------------------------------------------------
// RMS-norm ckv[0:256] and qd[0:384] in place (x * rsqrt(mean(x^2)+eps) * g),
// and write RoPE-rotated k_rope (ckv cols 256..287) to krope.
// One block per (b,s) row.
// ---------------------------------------------------------------------------
__global__ __launch_bounds__(256) void k_rmsrope(
    float* __restrict__ ckv, float* __restrict__ qd, float* __restrict__ krope,
    const float* __restrict__ gkv, const float* __restrict__ gq,
    const float* __restrict__ fcos, const float* __restrict__ fsin)
{
    __shared__ float red[256];
    int row = blockIdx.x, tid = threadIdx.x;
    int s = row % SEQ;
    float* cp = ckv + (size_t)row * KVW;
    float* qp = qd + (size_t)row * QC;
    float c0 = cp[tid];
    float q0 = qp[tid];
    float q1 = (tid < 128) ? qp[256 + tid] : 0.f;

    red[tid] = c0 * c0;
    __syncthreads();
    for (int o = 128; o; o >>= 1) { if (tid < o) red[tid] += red[tid + o]; __syncthreads(); }
    float inv1 = rsqrtf(red[0] * (1.f / 256.f) + EPS_RMS);
    __syncthreads();
    red[tid] = q0 * q0 + q1 * q1;
    __syncthreads();
    for (int o = 128; o; o >>= 1) { if (tid < o) red[tid] += red[tid + o]; __syncthreads(); }
    float inv2 = rsqrtf(red[0] * (1.f / 384.f) + EPS_RMS);

    cp[tid] = c0 * inv1 * gkv[tid];
    qp[tid] = q0 * inv2 * gq[tid];
    if (tid < 128) qp[256 + tid] = q1 * inv2 * gq[256 + tid];

    if (tid < 16) {  // rope pairs: pair i uses freq i%8, pos (s-1)%256
        float r0 = cp[256 + 2 * tid], r1 = cp[256 + 2 * tid + 1];
        float o0, o1;
        if (s == 0) { o0 = r0; o1 = r1; }
        else {
            int p = (s - 1) & 255;
            int j = tid & 7;
            float cc = fcos[p * 8 + j], sn = fsin[p * 8 + j];
            o0 = r0 * cc - r1 * sn;
            o1 = r0 * sn + r1 * cc;
        }
        krope[(size_t)row * ROPE_D + 2 * tid] = o0;
        krope[(size_t)row * ROPE_D + 2 * tid + 1] = o1;
    }
}

// ---------------------------------------------------------------------------
// Assemble Q/K/V layouts for attention (+ RoPE on q_rope part).
// Q,K: (B, 32, SEQ, 48)   V: (B, 16, SEQ, 64)
// Head H = 2h+e:  K main = kv[h*128 + e*32 + d]; K rope = krope[e*16 + d]
//                 Q main = qf[h*96  + e*32 + d]; Q rope = rope(qf[h*96+64+e*16+d])
//                 V      = kv[h*128 + 64 + d]
// ---------------------------------------------------------------------------
__global__ __launch_bounds__(256) void k_scatter(
    const float* __restrict__ kv, const float* __restrict__ qf,
    const float* __restrict__ krope,
    const float* __restrict__ fcos, const float* __restrict__ fsin,
    float* __restrict__ Qa, float* __restrict__ Ka, float* __restrict__ Va)
{
    int row = blockIdx.x, tid = threadIdx.x;
    int b = row / SEQ, s = row % SEQ;
    const float* kvp = kv + (size_t)row * 2048;
    const float* qfp = qf + (size_t)row * 1536;
    int p = (s - 1) & 255;
    bool rot = (s != 0);

    for (int t = tid; t < NH2 * QKD; t += 256) {
        int H = t / QKD, d = t % QKD;
        int h2 = H >> 1, e = H & 1;
        float v;
        if (d < 32) v = kvp[h2 * 128 + e * 32 + d];
        else        v = krope[(size_t)row * ROPE_D + e * 16 + (d - 32)];
        Ka[(((size_t)b * NH2 + H) * SEQ + s) * QKD + d] = v;
    }
    for (int t = tid; t < NHEAD * HD; t += 256) {
        int hh = t >> 6, d = t & 63;
        Va[(((size_t)b * NHEAD + hh) * SEQ + s) * HD + d] = kvp[hh * 128 + 64 + d];
    }
    for (int t = tid; t < NH2 * QKD; t += 256) {
        int H = t / QKD, d = t % QKD;
        int h2 = H >> 1, e = H & 1;
        float v;
        if (d < 32) v = qfp[h2 * 96 + e * 32 + d];
        else {
            int dd = d - 32, base = h2 * 96 + 64 + e * 16;
            if (rot) {
                int j = dd >> 1;
                float r0 = qfp[base + 2 * j], r1 = qfp[base + 2 * j + 1];
                float cc = fcos[p * 8 + j], sn = fsin[p * 8 + j];
                v = (dd & 1) ? (r0 * sn + r1 * cc) : (r0 * cc - r1 * sn);
            } else v = qfp[base + dd];
        }
        Qa[(((size_t)b * NH2 + H) * SEQ + s) * QKD + d] = v;
    }
}

// ---------------------------------------------------------------------------
// Cog-attention: one block = (b, pair-head h, 4 query rows). Wave w owns row w.
// Allowed cols: col 0, plus c>=1 with (c-1)%256 <= (r-1)%256 (all 4 segments).
// a1 = signed softmax(|s1|), a2 likewise; out = a1 - lam*a2 + G*lam over
// allowed cols (masked entries of a1/a2 are exactly 0). G = rowsum(a1)/SEQ.
// Fused head-RMS epilogue. attO layout: (B, SEQ, 16, 64).
// ---------------------------------------------------------------------------
__global__ __launch_bounds__(256) void k_attn(
    const float* __restrict__ Qa, const float* __restrict__ Ka,
    const float* __restrict__ Va, const float* __restrict__ ghead,
    const float* __restrict__ lq1, const float* __restrict__ lk1,
    const float* __restrict__ lq2, const float* __restrict__ lk2,
    float* __restrict__ attO)
{
    __shared__ float w1[4][SEQ];
    __shared__ float w2[4][SEQ];
    __shared__ float qs[4][96];
    __shared__ float s_lam;

    int bid = blockIdx.x;
    int rt = bid % RT_PER;
    int bh = bid / RT_PER;
    int h = bh % NHEAD, b = bh / NHEAD;
    int tid = threadIdx.x;
    int rr = tid >> 6;     // wave id = row-in-tile
    int lane = tid & 63;
    int r0 = rt * 4;
    int r = r0 + rr;
    bool rvalid = (r < SEQ);
    int rc = rvalid ? r : (SEQ - 1);
    int pr = (rc == 0) ? -1 : ((rc - 1) & 255);

    int pmax = -1;
    for (int i = 0; i < 4; ++i) {
        int ri = r0 + i;
        if (ri >= SEQ) break;
        int p = (ri == 0) ? -1 : ((ri - 1) & 255);
        pmax = max(pmax, p);
    }
    int qmax = pmax >> 6;                 // >= 0 always (every tile has pmax >= 0)
    int Lproc = 1 + (qmax + 1) * 256;

    for (int i = tid; i < 4 * 96; i += 256) {
        int rr2 = i / 96, d = i % 96;
        int e = d / 48, dd = d % 48;
        int ri = min(r0 + rr2, SEQ - 1);
        qs[rr2][d] = Qa[(((size_t)b * NH2 + 2 * h + e) * SEQ + ri) * QKD + dd];
    }
    if (tid == 0) {
        float a1 = 0, a2 = 0;
        for (int i = 0; i < 32; ++i) { a1 = fmaf(lq1[i], lk1[i], a1); a2 = fmaf(lq2[i], lk2[i], a2); }
        s_lam = __expf(a1) - __expf(a2) + LAMBDA_INIT;
    }
    __syncthreads();
    // everything below is per-wave (row-private LDS), no more barriers needed

    const float* kb1 = Ka + ((size_t)(b * NH2 + 2 * h)) * SEQ * QKD;
    const float* kb2 = Ka + ((size_t)(b * NH2 + 2 * h + 1)) * SEQ * QKD;

    if (lane == 0) {   // col 0 scores
        float a = 0, c2 = 0;
        for (int d = 0; d < QKD; ++d) { a = fmaf(qs[rr][d], kb1[d], a); c2 = fmaf(qs[rr][48 + d], kb2[d], c2); }
        w1[rr][0] = a * KSCALE;
        w2[rr][0] = c2 * KSCALE;
    }
    for (int q = 0; q <= qmax; ++q) {
        int j = q * 64 + lane;
        for (int seg = 0; seg < 4; ++seg) {
            int col = seg * 256 + 1 + j;
            int idx = 1 + q * 256 + seg * 64 + lane;
            float a = 0, c2 = 0;
            if (j <= pr) {
                const float* k1p = kb1 + (size_t)col * QKD;
                const float* k2p = kb2 + (size_t)col * QKD;
#pragma unroll
                for (int d = 0; d < QKD; ++d) { a = fmaf(qs[rr][d], k1p[d], a); c2 = fmaf(qs[rr][48 + d], k2p[d], c2); }
            }
            w1[rr][idx] = a * KSCALE;
            w2[rr][idx] = c2 * KSCALE;
        }
    }

    // wave-level max of |score| over allowed entries
    float m1 = 0.f, m2 = 0.f;
    for (int idx = lane; idx < Lproc; idx += 64) {
        bool al = (idx == 0);
        if (!al) { int t = idx - 1; int j2 = ((t >> 8) << 6) | (t & 63); al = (j2 <= pr); }
        if (al) { m1 = fmaxf(m1, fabsf(w1[rr][idx])); m2 = fmaxf(m2, fabsf(w2[rr][idx])); }
    }
    for (int off = 32; off; off >>= 1) { m1 = fmaxf(m1, __shfl_xor(m1, off)); m2 = fmaxf(m2, __shfl_xor(m2, off)); }

    // signed exp + sums
    float d1 = 0.f, d2 = 0.f, gs = 0.f;
    for (int idx = lane; idx < Lproc; idx += 64) {
        bool al = (idx == 0);
        if (!al) { int t = idx - 1; int j2 = ((t >> 8) << 6) | (t & 63); al = (j2 <= pr); }
        if (al) {
            float a = w1[rr][idx];
            float pa = __expf(fabsf(a) - m1);
            float sa = (a > 0.f) ? pa : ((a < 0.f) ? -pa : 0.f);
            d1 += pa; gs += sa; w1[rr][idx] = sa;
            float bb = w2[rr][idx];
            float pb = __expf(fabsf(bb) - m2);
            float sb = (bb > 0.f) ? pb : ((bb < 0.f) ? -pb : 0.f);
            d2 += pb; w2[rr][idx] = sb;
        }
    }
    for (int off = 32; off; off >>= 1) { d1 += __shfl_xor(d1, off); d2 += __shfl_xor(d2, off); gs += __shfl_xor(gs, off); }

    float lam = s_lam;
    float i1 = 1.f / d1, i2 = 1.f / d2;
    float Gl = gs * i1 * (1.0f / (float)SEQ) * lam;

    for (int idx = lane; idx < Lproc; idx += 64) {
        bool al = (idx == 0);
        if (!al) { int t = idx - 1; int j2 = ((t >> 8) << 6) | (t & 63); al = (j2 <= pr); }
        float v = al ? (w1[rr][idx] * i1 - lam * w2[rr][idx] * i2 + Gl) : 0.f;
        w1[rr][idx] = v;
    }

    // PV: thread (rr, d=lane) accumulates out dim d
    const float* vb = Va + ((size_t)(b * NHEAD + h)) * SEQ * HD;
    float o = w1[rr][0] * vb[lane];
    for (int q = 0; q <= qmax; ++q)
        for (int seg = 0; seg < 4; ++seg) {
            int base = 1 + q * 256 + seg * 64;
            int colb = seg * 256 + 1 + q * 64;
            const float* vp = vb + (size_t)colb * HD + lane;
#pragma unroll 8
            for (int jj = 0; jj < 64; ++jj)
                o = fmaf(w1[rr][base + jj], vp[(size_t)jj * HD], o);
        }

    // fused head-RMS (over 64 dims = 64 lanes of this wave)
    float sq = o * o;
    for (int off = 32; off; off >>= 1) sq += __shfl_xor(sq, off);
    float inv = rsqrtf(sq * (1.f / (float)HD) + EPS_HEAD);
    if (rvalid)
        attO[(((size_t)b * SEQ + r) * NHEAD + h) * HD + lane] = o * inv * ghead[lane];
}

// ---------------------------------------------------------------------------
extern "C" void kernel_launch(void* const* d_in, const int* in_sizes, int n_in,
                              void* d_out, int out_size, void* d_ws, size_t ws_size,
                              hipStream_t stream)
{
    const float* x    = (const float*)d_in[0];
    // d_in[1] = mask (unused; mask is analytic)
    const float* fcos = (const float*)d_in[2];
    const float* fsin = (const float*)d_in[3];
    const float* Wkvd = (const float*)d_in[4];
    const float* Wqd  = (const float*)d_in[5];
    const float* Wkvu = (const float*)d_in[6];
    const float* Wqu  = (const float*)d_in[7];
    const float* Wo   = (const float*)d_in[8];
    const float* gkv  = (const float*)d_in[9];
    const float* gq   = (const float*)d_in[10];
    const float* gh   = (const float*)d_in[11];
    const float* lq1  = (const float*)d_in[12];
    const float* lk1  = (const float*)d_in[13];
    const float* lq2  = (const float*)d_in[14];
    const float* lk2  = (const float*)d_in[15];
    float* out = (float*)d_out;

    const int R = BATCH * SEQ;  // 2050
    float* ws = (float*)d_ws;
    float* ckv   = ws;  ws += (size_t)R * KVW;            // 2050*288
    float* qd    = ws;  ws += (size_t)R * QC;             // 2050*384
    float* krope = ws;  ws += (size_t)R * ROPE_D;         // 2050*32
    float* kv    = ws;  ws += (size_t)R * 2048;           // 2050*2048
    float* qf    = ws;  ws += (size_t)R * 1536;           // 2050*1536
    float* Qa    = ws;  ws += (size_t)BATCH * NH2 * SEQ * QKD;
    float* Ka    = ws;  ws += (size_t)BATCH * NH2 * SEQ * QKD;
    float* Va    = ws;  ws += (size_t)BATCH * NHEAD * SEQ * HD;
    float* attO  = kv;  // kv is dead after k_scatter; reuse for attO (2050*1024)

    dim3 blk(256);
    auto gemm = [&](const float* A, const float* Bm, float* C,
                    int M, int N, int K, int ldA, int ldB, int ldC) {
        dim3 g((N + 63) / 64, (M + 127) / 128);
        gemm_f32<<<g, blk, 0, stream>>>(A, Bm, C, M, N, K, ldA, ldB, ldC);
    };

    gemm(x, Wkvd, ckv, R, KVW, DM, DM, KVW, KVW);      // x @ W_kv_down
    gemm(x, Wqd, qd, R, QC, DM, DM, QC, QC);           // x @ W_q_down
    k_rmsrope<<<R, blk, 0, stream>>>(ckv, qd, krope, gkv, gq, fcos, fsin);
    gemm(ckv, Wkvu, kv, R, 2048, KVC, KVW, 2048, 2048); // rms(c_kv) @ W_kv_up
    gemm(qd, Wqu, qf, R, 1536, QC, QC, 1536, 1536);     // rms(qd) @ W_q_up
    k_scatter<<<R, blk, 0, stream>>>(kv, qf, krope, fcos, fsin, Qa, Ka, Va);
    k_attn<<<BATCH * NHEAD * RT_PER, blk, 0, stream>>>(Qa, Ka, Va, gh,
                                                       lq1, lk1, lq2, lk2, attO);
    gemm(attO, Wo, out, R, DM, DM, DM, DM, DM);         // out proj
}

// Round 4
// 637.164 us; speedup vs baseline: 2.6057x; 2.6057x over previous
//
#include <hip/hip_runtime.h>
#include <hip/hip_bf16.h>
#include <math.h>

#define NHEAD 16
#define SEQ 1025
#define BATCH 2
#define NH2 32
#define KSCALE (1.0f/48.0f)
#define EPS_RMS 1.1920929e-07f
#define EPS_HEAD 1e-05f
#define LAMBDA_INIT 0.2f
#define R_TOT (BATCH*SEQ)

typedef __attribute__((ext_vector_type(8))) short bf16x8;
typedef __attribute__((ext_vector_type(4))) float f32x4;
typedef __attribute__((ext_vector_type(4))) int  i32x4;

static __device__ __forceinline__ unsigned short f2bf(float x) {
    unsigned int u = __float_as_uint(x);
    unsigned int r = (u + 0x7fffu + ((u >> 16) & 1u)) >> 16;
    return (unsigned short)r;
}
static __device__ __forceinline__ float bf2f(unsigned short h) {
    return __uint_as_float(((unsigned int)h) << 16);
}
static __device__ __forceinline__ void split3(float v, unsigned short& h,
                                              unsigned short& m, unsigned short& l) {
    h = f2bf(v); float r1 = v - bf2f(h);
    m = f2bf(r1); float r2 = r1 - bf2f(m);
    l = f2bf(r2);
}
static __device__ __forceinline__ f32x4 MFMA(bf16x8 a, bf16x8 b, f32x4 c) {
    return __builtin_amdgcn_mfma_f32_16x16x32_bf16(a, b, c, 0, 0, 0);
}

// ---------------------------------------------------------------------------
// x fp32 -> 3-plane bf16
// ---------------------------------------------------------------------------
__global__ __launch_bounds__(256) void conv_x3(const float* __restrict__ x,
    unsigned short* __restrict__ xh, unsigned short* __restrict__ xm,
    unsigned short* __restrict__ xl, int total)
{
    int i = (blockIdx.x * 256 + threadIdx.x) * 4;
    if (i >= total) return;
    f32x4 v = *(const f32x4*)(x + i);
#pragma unroll
    for (int j = 0; j < 4; ++j) {
        unsigned short h, m, l;
        split3(v[j], h, m, l);
        xh[i + j] = h; xm[i + j] = m; xl[i + j] = l;
    }
}

// ---------------------------------------------------------------------------
// W[K,N] fp32 -> 3-plane bf16 transposed [N,K]
// ---------------------------------------------------------------------------
__global__ __launch_bounds__(256) void conv_wt3(const float* __restrict__ W,
    unsigned short* __restrict__ Th, unsigned short* __restrict__ Tm,
    unsigned short* __restrict__ Tl, int K, int N)
{
    __shared__ float tile[32][33];
    int n0 = blockIdx.x * 32, k0 = blockIdx.y * 32;
    int tx = threadIdx.x & 31, ty = threadIdx.x >> 5;
    for (int kk = ty; kk < 32; kk += 8) {
        int k = k0 + kk, n = n0 + tx;
        tile[kk][tx] = (k < K && n < N) ? W[(size_t)k * N + n] : 0.f;
    }
    __syncthreads();
    for (int nn = ty; nn < 32; nn += 8) {
        int n = n0 + nn, k = k0 + tx;
        if (n < N && k < K) {
            unsigned short h, m, l;
            split3(tile[tx][nn], h, m, l);
            Th[(size_t)n * K + k] = h;
            Tm[(size_t)n * K + k] = m;
            Tl[(size_t)n * K + k] = l;
        }
    }
}

// single-plane transpose-convert (for W_o)
__global__ __launch_bounds__(256) void conv_wt1(const float* __restrict__ W,
    unsigned short* __restrict__ Th, int K, int N)
{
    __shared__ float tile[32][33];
    int n0 = blockIdx.x * 32, k0 = blockIdx.y * 32;
    int tx = threadIdx.x & 31, ty = threadIdx.x >> 5;
    for (int kk = ty; kk < 32; kk += 8) {
        int k = k0 + kk, n = n0 + tx;
        tile[kk][tx] = (k < K && n < N) ? W[(size_t)k * N + n] : 0.f;
    }
    __syncthreads();
    for (int nn = ty; nn < 32; nn += 8) {
        int n = n0 + nn, k = k0 + tx;
        if (n < N && k < K) Th[(size_t)n * K + k] = f2bf(tile[tx][nn]);
    }
}

// ---------------------------------------------------------------------------
// 3-way split MFMA GEMM:  C = A @ B^T  (B transposed [N,K]), 6 products
// (hh, hm, mh, hl, mm, lh) -> ~2^-24 relative accuracy.
// EPI=0: plain fp32 C.  EPI=1: kv-up scatter (K 3-plane + V bf16).
// EPI=2: q-up scatter (rope via lane-pair shfl, KSCALE, Q 3-plane).
// ---------------------------------------------------------------------------
template<int EPI>
__global__ __launch_bounds__(256) void gemm3(
    const unsigned short* __restrict__ Ah, const unsigned short* __restrict__ Am,
    const unsigned short* __restrict__ Al,
    const unsigned short* __restrict__ Bh, const unsigned short* __restrict__ Bm,
    const unsigned short* __restrict__ Bl,
    float* __restrict__ C,
    unsigned short* __restrict__ D0, unsigned short* __restrict__ D1,
    unsigned short* __restrict__ D2, unsigned short* __restrict__ D3,
    const float* __restrict__ fcos, const float* __restrict__ fsin,
    int M, int N, int K)
{
    __shared__ unsigned short LA[3][128 * 40];
    __shared__ unsigned short LB[3][128 * 40];

    int tid = threadIdx.x;
    int wid = tid >> 6, lane = tid & 63;
    int la = lane & 15, lb = lane >> 4;
    int bm = blockIdx.y * 128, bn = blockIdx.x * 128;
    int wr = (wid >> 1) * 64, wc = (wid & 1) * 64;

    const unsigned short* APl[3] = {Ah, Am, Al};
    const unsigned short* BPl[3] = {Bh, Bm, Bl};

    f32x4 acc[4][4];
#pragma unroll
    for (int m = 0; m < 4; ++m)
#pragma unroll
        for (int n = 0; n < 4; ++n) acc[m][n] = (f32x4){0.f, 0.f, 0.f, 0.f};

    for (int k0 = 0; k0 < K; k0 += 32) {
        __syncthreads();
#pragma unroll
        for (int p = 0; p < 3; ++p) {
#pragma unroll
            for (int i0 = 0; i0 < 2; ++i0) {
                int i = tid + i0 * 256;
                int row = i >> 2, ko = (i & 3) * 8;
                i32x4 z = {0, 0, 0, 0};
                i32x4 v = z, w = z;
                int gr = bm + row;
                if (gr < M) v = *(const i32x4*)(APl[p] + (size_t)gr * K + k0 + ko);
                *(i32x4*)&LA[p][row * 40 + ko] = v;
                int gn = bn + row;
                if (gn < N) w = *(const i32x4*)(BPl[p] + (size_t)gn * K + k0 + ko);
                *(i32x4*)&LB[p][row * 40 + ko] = w;
            }
        }
        __syncthreads();
        bf16x8 a_[3][4], b_[3][4];
#pragma unroll
        for (int p = 0; p < 3; ++p) {
#pragma unroll
            for (int m = 0; m < 4; ++m)
                a_[p][m] = *(const bf16x8*)&LA[p][(wr + m * 16 + la) * 40 + lb * 8];
#pragma unroll
            for (int n = 0; n < 4; ++n)
                b_[p][n] = *(const bf16x8*)&LB[p][(wc + n * 16 + la) * 40 + lb * 8];
        }
#pragma unroll
        for (int m = 0; m < 4; ++m)
#pragma unroll
            for (int n = 0; n < 4; ++n) {
                acc[m][n] = MFMA(a_[0][m], b_[0][n], acc[m][n]);
                acc[m][n] = MFMA(a_[0][m], b_[1][n], acc[m][n]);
                acc[m][n] = MFMA(a_[1][m], b_[0][n], acc[m][n]);
                acc[m][n] = MFMA(a_[0][m], b_[2][n], acc[m][n]);
                acc[m][n] = MFMA(a_[1][m], b_[1][n], acc[m][n]);
                acc[m][n] = MFMA(a_[2][m], b_[0][n], acc[m][n]);
            }
    }

#pragma unroll
    for (int m = 0; m < 4; ++m)
#pragma unroll
        for (int n = 0; n < 4; ++n) {
            int gc = bn + wc + n * 16 + la;
#pragma unroll
            for (int r = 0; r < 4; ++r) {
                int gr = bm + wr + m * 16 + lb * 4 + r;
                float v = acc[m][n][r];
                if (EPI == 0) {
                    if (gr < M && gc < N) C[(size_t)gr * N + gc] = v;
                } else if (EPI == 1) {
                    if (gr < M) {
                        int b = gr / SEQ, s = gr - b * SEQ;
                        int h2 = gc >> 7, rem = gc & 127;
                        if (rem < 64) {
                            int H = 2 * h2 + (rem >> 5), d = rem & 31;
                            size_t idx = (((size_t)b * NH2 + H) * SEQ + s) * 48 + d;
                            unsigned short hh, mm2, ll;
                            split3(v, hh, mm2, ll);
                            D0[idx] = hh; D1[idx] = mm2; D2[idx] = ll;
                        } else {
                            D3[(((size_t)b * NHEAD + h2) * SEQ + s) * 64 + (rem - 64)] = f2bf(v);
                        }
                    }
                } else {
                    // EPI == 2: q scatter with rope. shfl BEFORE any guard.
                    float pv = __shfl_xor(v, 1);
                    if (gr < M) {
                        int b = gr / SEQ, s = gr - b * SEQ;
                        int h2 = gc / 96, rem = gc - h2 * 96;
                        int H, d; float outv;
                        if (rem < 64) {
                            H = 2 * h2 + (rem >> 5); d = rem & 31; outv = v;
                        } else {
                            int dd = rem - 64;
                            int e = dd >> 4, j = (dd & 15) >> 1;
                            H = 2 * h2 + e; d = 32 + (dd & 15);
                            if (s != 0) {
                                int p = (s - 1) & 255;
                                float cc = fcos[p * 8 + j], sn = fsin[p * 8 + j];
                                outv = ((la & 1) == 0) ? (v * cc - pv * sn)
                                                       : (pv * sn + v * cc);
                            } else outv = v;
                        }
                        outv *= KSCALE;
                        size_t idx = (((size_t)b * NH2 + H) * SEQ + s) * 48 + d;
                        unsigned short hh, mm2, ll;
                        split3(outv, hh, mm2, ll);
                        D0[idx] = hh; D1[idx] = mm2; D2[idx] = ll;
                    }
                }
            }
        }
}

// ---------------------------------------------------------------------------
// 1-plane bf16 GEMM for the output projection.
// ---------------------------------------------------------------------------
__global__ __launch_bounds__(256) void gemm1(
    const unsigned short* __restrict__ Ah, const unsigned short* __restrict__ Bh,
    float* __restrict__ C, int M, int N, int K)
{
    __shared__ unsigned short As[128 * 40];
    __shared__ unsigned short Bs[128 * 40];
    int tid = threadIdx.x;
    int wid = tid >> 6, lane = tid & 63;
    int la = lane & 15, lb = lane >> 4;
    int bm = blockIdx.y * 128, bn = blockIdx.x * 128;
    int wr = (wid >> 1) * 64, wc = (wid & 1) * 64;
    f32x4 acc[4][4];
#pragma unroll
    for (int m = 0; m < 4; ++m)
#pragma unroll
        for (int n = 0; n < 4; ++n) acc[m][n] = (f32x4){0.f, 0.f, 0.f, 0.f};
    for (int k0 = 0; k0 < K; k0 += 32) {
        __syncthreads();
#pragma unroll
        for (int i0 = 0; i0 < 2; ++i0) {
            int i = tid + i0 * 256;
            int row = i >> 2, ko = (i & 3) * 8;
            i32x4 z = {0, 0, 0, 0};
            i32x4 v = z, w = z;
            int gr = bm + row;
            if (gr < M) v = *(const i32x4*)(Ah + (size_t)gr * K + k0 + ko);
            *(i32x4*)&As[row * 40 + ko] = v;
            int gn = bn + row;
            if (gn < N) w = *(const i32x4*)(Bh + (size_t)gn * K + k0 + ko);
            *(i32x4*)&Bs[row * 40 + ko] = w;
        }
        __syncthreads();
        bf16x8 a_[4], b_[4];
#pragma unroll
        for (int m = 0; m < 4; ++m) a_[m] = *(const bf16x8*)&As[(wr + m * 16 + la) * 40 + lb * 8];
#pragma unroll
        for (int n = 0; n < 4; ++n) b_[n] = *(const bf16x8*)&Bs[(wc + n * 16 + la) * 40 + lb * 8];
#pragma unroll
        for (int m = 0; m < 4; ++m)
#pragma unroll
            for (int n = 0; n < 4; ++n) acc[m][n] = MFMA(a_[m], b_[n], acc[m][n]);
    }
#pragma unroll
    for (int m = 0; m < 4; ++m)
#pragma unroll
        for (int n = 0; n < 4; ++n) {
            int gc = bn + wc + n * 16 + la;
            if (gc >= N) continue;
#pragma unroll
            for (int r = 0; r < 4; ++r) {
                int gr = bm + wr + m * 16 + lb * 4 + r;
                if (gr < M) C[(size_t)gr * N + gc] = acc[m][n][r];
            }
        }
}

// ---------------------------------------------------------------------------
// RMS-norm both streams + write K-rope dims (3-plane) directly.
// ckvqd: [R][672] fp32 (0..255 ckv | 256..287 rope | 288..671 qd)
// ---------------------------------------------------------------------------
__global__ __launch_bounds__(256) void k_rmsrope3(
    const float* __restrict__ ckvqd,
    unsigned short* __restrict__ cnh, unsigned short* __restrict__ cnm,
    unsigned short* __restrict__ cnl,
    unsigned short* __restrict__ qnh, unsigned short* __restrict__ qnm,
    unsigned short* __restrict__ qnl,
    unsigned short* __restrict__ Kah, unsigned short* __restrict__ Kam,
    unsigned short* __restrict__ Kal,
    const float* __restrict__ gkv, const float* __restrict__ gq,
    const float* __restrict__ fcos, const float* __restrict__ fsin)
{
    __shared__ float red[256];
    __shared__ float rot[32];
    int row = blockIdx.x, tid = threadIdx.x;
    int b = row / SEQ, s = row - b * SEQ;
    const float* cp = ckvqd + (size_t)row * 672;
    float c0 = cp[tid];
    float q0 = cp[288 + tid];
    float q1 = (tid < 128) ? cp[544 + tid] : 0.f;

    red[tid] = c0 * c0;
    __syncthreads();
    for (int o = 128; o; o >>= 1) { if (tid < o) red[tid] += red[tid + o]; __syncthreads(); }
    float inv1 = rsqrtf(red[0] * (1.f / 256.f) + EPS_RMS);
    __syncthreads();
    red[tid] = q0 * q0 + q1 * q1;
    __syncthreads();
    for (int o = 128; o; o >>= 1) { if (tid < o) red[tid] += red[tid + o]; __syncthreads(); }
    float inv2 = rsqrtf(red[0] * (1.f / 384.f) + EPS_RMS);

    unsigned short h, m, l;
    split3(c0 * inv1 * gkv[tid], h, m, l);
    size_t ci = (size_t)row * 256 + tid;
    cnh[ci] = h; cnm[ci] = m; cnl[ci] = l;

    split3(q0 * inv2 * gq[tid], h, m, l);
    size_t qi = (size_t)row * 384 + tid;
    qnh[qi] = h; qnm[qi] = m; qnl[qi] = l;
    if (tid < 128) {
        split3(q1 * inv2 * gq[256 + tid], h, m, l);
        qnh[qi + 256] = h; qnm[qi + 256] = m; qnl[qi + 256] = l;
    }

    if (tid < 16) {  // rotate rope pairs (16 pairs of the 32-dim rope vec)
        float r0 = cp[256 + 2 * tid], r1 = cp[256 + 2 * tid + 1];
        float o0, o1;
        if (s == 0) { o0 = r0; o1 = r1; }
        else {
            int p = (s - 1) & 255;
            int j = tid & 7;
            float cc = fcos[p * 8 + j], sn = fsin[p * 8 + j];
            o0 = r0 * cc - r1 * sn;
            o1 = r0 * sn + r1 * cc;
        }
        rot[2 * tid] = o0; rot[2 * tid + 1] = o1;
    }
    __syncthreads();
    for (int t = tid; t < 512; t += 256) {   // 32 heads x 16 dims
        int H = t >> 4, dd = t & 15;
        int e = H & 1;
        split3(rot[e * 16 + dd], h, m, l);
        size_t idx = (((size_t)b * NH2 + H) * SEQ + s) * 48 + 32 + dd;
        Kah[idx] = h; Kam[idx] = m; Kal[idx] = l;
    }
}

// ---------------------------------------------------------------------------
// MFMA cog-attention, 3-way-split QK^T (12 MFMAs / 16x16 score tile).
// K1 and K2 staged sequentially through shared LDS planes (fits 46 KB).
// ---------------------------------------------------------------------------
__global__ __launch_bounds__(256) void k_attn3(
    const unsigned short* __restrict__ Qah, const unsigned short* __restrict__ Qam,
    const unsigned short* __restrict__ Qal,
    const unsigned short* __restrict__ Kah, const unsigned short* __restrict__ Kam,
    const unsigned short* __restrict__ Kal,
    const unsigned short* __restrict__ Va, const float* __restrict__ ghead,
    const float* __restrict__ lq1, const float* __restrict__ lk1,
    const float* __restrict__ lq2, const float* __restrict__ lk2,
    unsigned short* __restrict__ attO)
{
    __shared__ unsigned short Kh[64 * 72];
    __shared__ unsigned short Km[64 * 72];
    __shared__ unsigned short Kl[64 * 72];
    __shared__ unsigned short Vt[64 * 72];
    __shared__ unsigned short Pl[4][16 * 72];

    int bid = blockIdx.x;
    int rt = bid % 17;
    int bh = bid / 17;
    int h = bh & 15, b = bh >> 4;
    int tid = threadIdx.x, wid = tid >> 6, lane = tid & 63;
    int la = lane & 15, lb = lane >> 4;
    int r0 = rt * 64, r0w = r0 + wid * 16;

    float e1 = 0.f, e2 = 0.f;
    for (int i = 0; i < 32; ++i) { e1 = fmaf(lq1[i], lk1[i], e1); e2 = fmaf(lq2[i], lk2[i], e2); }
    float lam = __expf(e1) - __expf(e2) + LAMBDA_INIT;

    int pr[4];
#pragma unroll
    for (int g = 0; g < 4; ++g) {
        int r = r0w + lb * 4 + g;
        pr[g] = (r >= 1 && r < SEQ) ? ((r - 1) & 255) : -1;
    }
    int rA = r0w + la;
    int prA = (rA >= 1 && rA < SEQ) ? ((rA - 1) & 255) : -1;

    int prm = -1;
    for (int i = 0; i < 64; ++i) {
        int r = r0 + i;
        if (r >= 1 && r < SEQ) { int p = (r - 1) & 255; prm = p > prm ? p : prm; }
    }

    const size_t hb1 = ((size_t)(b * NH2 + 2 * h)) * SEQ * 48;
    const size_t hb2 = ((size_t)(b * NH2 + 2 * h + 1)) * SEQ * 48;
    const unsigned short* vp = Va + ((size_t)(b * NHEAD + h)) * SEQ * 64;

    int qrow = r0w + la; if (qrow > SEQ - 1) qrow = SEQ - 1;
    bf16x8 zf;
#pragma unroll
    for (int u = 0; u < 8; ++u) zf[u] = 0;
    bf16x8 q1[3][2], q2[3][2];
    {
        const unsigned short* QPl[3] = {Qah, Qam, Qal};
#pragma unroll
        for (int p = 0; p < 3; ++p)
#pragma unroll
            for (int f = 0; f < 2; ++f) {
                if (f == 0 || lb < 2) {
                    q1[p][f] = *(const bf16x8*)(QPl[p] + hb1 + (size_t)qrow * 48 + 32 * f + lb * 8);
                    q2[p][f] = *(const bf16x8*)(QPl[p] + hb2 + (size_t)qrow * 48 + 32 * f + lb * 8);
                } else { q1[p][f] = zf; q2[p][f] = zf; }
            }
    }

    f32x4 O1[4], O2[4], VS[4];
#pragma unroll
    for (int nd = 0; nd < 4; ++nd) {
        O1[nd] = (f32x4){0.f, 0.f, 0.f, 0.f};
        O2[nd] = (f32x4){0.f, 0.f, 0.f, 0.f};
        VS[nd] = (f32x4){0.f, 0.f, 0.f, 0.f};
    }
    float m1[4] = {0.f, 0.f, 0.f, 0.f}, m2[4] = {0.f, 0.f, 0.f, 0.f};
    float d1[4] = {0.f, 0.f, 0.f, 0.f}, d2[4] = {0.f, 0.f, 0.f, 0.f};
    float gs[4] = {0.f, 0.f, 0.f, 0.f};
    f32x4 z = (f32x4){0.f, 0.f, 0.f, 0.f};

    for (int j = 0; j < 17; ++j) {
        bool need;
        if (j == 16) need = (prm >= 255);
        else { int jj = j & 3; need = (jj == 0) || (prm >= 64 * jj - 1); }
        if (!need) continue;
        int c0 = j * 64;

        // ---- stage K1 planes ----
        __syncthreads();
#pragma unroll
        for (int p = 0; p < 3; ++p) {
            const unsigned short* src = (p == 0) ? Kah : ((p == 1) ? Kam : Kal);
            unsigned short* dst = (p == 0) ? Kh : ((p == 1) ? Km : Kl);
            for (int i = tid; i < 512; i += 256) {
                int c = i >> 3, u = i & 7;
                int gc = c0 + c; if (gc > SEQ - 1) gc = SEQ - 1;
                i32x4 v = {0, 0, 0, 0};
                if (u < 6) v = *(const i32x4*)(src + hb1 + (size_t)gc * 48 + u * 8);
                *(i32x4*)&dst[c * 72 + u * 8] = v;
            }
        }
        __syncthreads();

        // ---- scores S1 ----
        f32x4 s1[4], s2[4];
#pragma unroll
        for (int n = 0; n < 4; ++n) {
            bf16x8 kh0 = *(const bf16x8*)&Kh[(n * 16 + la) * 72 + lb * 8];
            bf16x8 kh1 = *(const bf16x8*)&Kh[(n * 16 + la) * 72 + 32 + lb * 8];
            bf16x8 km0 = *(const bf16x8*)&Km[(n * 16 + la) * 72 + lb * 8];
            bf16x8 km1 = *(const bf16x8*)&Km[(n * 16 + la) * 72 + 32 + lb * 8];
            bf16x8 kl0 = *(const bf16x8*)&Kl[(n * 16 + la) * 72 + lb * 8];
            bf16x8 kl1 = *(const bf16x8*)&Kl[(n * 16 + la) * 72 + 32 + lb * 8];
            f32x4 s = z;
            s = MFMA(q1[0][0], kh0, s); s = MFMA(q1[0][1], kh1, s);
            s = MFMA(q1[0][0], km0, s); s = MFMA(q1[0][1], km1, s);
            s = MFMA(q1[1][0], kh0, s); s = MFMA(q1[1][1], kh1, s);
            s = MFMA(q1[0][0], kl0, s); s = MFMA(q1[0][1], kl1, s);
            s = MFMA(q1[1][0], km0, s); s = MFMA(q1[1][1], km1, s);
            s = MFMA(q1[2][0], kh0, s); s = MFMA(q1[2][1], kh1, s);
            s1[n] = s;
        }

        // ---- stage K2 planes + V transpose ----
        __syncthreads();
#pragma unroll
        for (int p = 0; p < 3; ++p) {
            const unsigned short* src = (p == 0) ? Kah : ((p == 1) ? Kam : Kal);
            unsigned short* dst = (p == 0) ? Kh : ((p == 1) ? Km : Kl);
            for (int i = tid; i < 512; i += 256) {
                int c = i >> 3, u = i & 7;
                int gc = c0 + c; if (gc > SEQ - 1) gc = SEQ - 1;
                i32x4 v = {0, 0, 0, 0};
                if (u < 6) v = *(const i32x4*)(src + hb2 + (size_t)gc * 48 + u * 8);
                *(i32x4*)&dst[c * 72 + u * 8] = v;
            }
        }
        for (int i = tid; i < 512; i += 256) {
            int c = i >> 3, ko = (i & 7) * 8;
            int gc = c0 + c; if (gc > SEQ - 1) gc = SEQ - 1;
            i32x4 vv = *(const i32x4*)(vp + (size_t)gc * 64 + ko);
            unsigned short tmp[8];
            *(i32x4*)tmp = vv;
#pragma unroll
            for (int u = 0; u < 8; ++u) Vt[(ko + u) * 72 + c] = tmp[u];
        }
        __syncthreads();

        // ---- scores S2 ----
#pragma unroll
        for (int n = 0; n < 4; ++n) {
            bf16x8 kh0 = *(const bf16x8*)&Kh[(n * 16 + la) * 72 + lb * 8];
            bf16x8 kh1 = *(const bf16x8*)&Kh[(n * 16 + la) * 72 + 32 + lb * 8];
            bf16x8 km0 = *(const bf16x8*)&Km[(n * 16 + la) * 72 + lb * 8];
            bf16x8 km1 = *(const bf16x8*)&Km[(n * 16 + la) * 72 + 32 + lb * 8];
            bf16x8 kl0 = *(const bf16x8*)&Kl[(n * 16 + la) * 72 + lb * 8];
            bf16x8 kl1 = *(const bf16x8*)&Kl[(n * 16 + la) * 72 + 32 + lb * 8];
            f32x4 s = z;
            s = MFMA(q2[0][0], kh0, s); s = MFMA(q2[0][1], kh1, s);
            s = MFMA(q2[0][0], km0, s); s = MFMA(q2[0][1], km1, s);
            s = MFMA(q2[1][0], kh0, s); s = MFMA(q2[1][1], kh1, s);
            s = MFMA(q2[0][0], kl0, s); s = MFMA(q2[0][1], kl1, s);
            s = MFMA(q2[1][0], km0, s); s = MFMA(q2[1][1], km1, s);
            s = MFMA(q2[2][0], kh0, s); s = MFMA(q2[2][1], kh1, s);
            s2[n] = s;
        }

        // ---- masks + online signed softmax ----
        bool alw[4][4];
        float tm1[4] = {0.f, 0.f, 0.f, 0.f}, tm2[4] = {0.f, 0.f, 0.f, 0.f};
#pragma unroll
        for (int n = 0; n < 4; ++n) {
            int c = c0 + n * 16 + la;
#pragma unroll
            for (int g = 0; g < 4; ++g) {
                bool al = (c == 0) || (c < SEQ && ((c - 1) & 255) <= pr[g]);
                alw[n][g] = al;
                if (al) {
                    tm1[g] = fmaxf(tm1[g], fabsf(s1[n][g]));
                    tm2[g] = fmaxf(tm2[g], fabsf(s2[n][g]));
                }
            }
        }
#pragma unroll
        for (int off = 1; off < 16; off <<= 1) {
#pragma unroll
            for (int g = 0; g < 4; ++g) {
                tm1[g] = fmaxf(tm1[g], __shfl_xor(tm1[g], off));
                tm2[g] = fmaxf(tm2[g], __shfl_xor(tm2[g], off));
            }
        }
        float sc1[4], sc2[4];
#pragma unroll
        for (int g = 0; g < 4; ++g) {
            float mn = fmaxf(m1[g], tm1[g]); sc1[g] = __expf(m1[g] - mn); m1[g] = mn;
            float mn2 = fmaxf(m2[g], tm2[g]); sc2[g] = __expf(m2[g] - mn2); m2[g] = mn2;
        }
#pragma unroll
        for (int nd = 0; nd < 4; ++nd)
#pragma unroll
            for (int g = 0; g < 4; ++g) { O1[nd][g] *= sc1[g]; O2[nd][g] *= sc2[g]; }
#pragma unroll
        for (int g = 0; g < 4; ++g) { d1[g] *= sc1[g]; gs[g] *= sc1[g]; d2[g] *= sc2[g]; }

        float ld1[4] = {0.f, 0.f, 0.f, 0.f}, ld2[4] = {0.f, 0.f, 0.f, 0.f},
              lgs[4] = {0.f, 0.f, 0.f, 0.f};
        unsigned short p1v[4][4], p2v[4][4];
#pragma unroll
        for (int n = 0; n < 4; ++n)
#pragma unroll
            for (int g = 0; g < 4; ++g) {
                float a = s1[n][g];
                if (alw[n][g]) {
                    float pa = __expf(fabsf(a) - m1[g]);
                    float sa = (a > 0.f) ? pa : ((a < 0.f) ? -pa : 0.f);
                    ld1[g] += pa; lgs[g] += sa; p1v[n][g] = f2bf(sa);
                } else p1v[n][g] = 0;
                float bb = s2[n][g];
                if (alw[n][g]) {
                    float pb = __expf(fabsf(bb) - m2[g]);
                    float sb = (bb > 0.f) ? pb : ((bb < 0.f) ? -pb : 0.f);
                    ld2[g] += pb; p2v[n][g] = f2bf(sb);
                } else p2v[n][g] = 0;
            }
#pragma unroll
        for (int off = 1; off < 16; off <<= 1) {
#pragma unroll
            for (int g = 0; g < 4; ++g) {
                ld1[g] += __shfl_xor(ld1[g], off);
                ld2[g] += __shfl_xor(ld2[g], off);
                lgs[g] += __shfl_xor(lgs[g], off);
            }
        }
#pragma unroll
        for (int g = 0; g < 4; ++g) { d1[g] += ld1[g]; gs[g] += lgs[g]; d2[g] += ld2[g]; }

        // ---- P1 -> A-frags via wave-private LDS ----
#pragma unroll
        for (int n = 0; n < 4; ++n)
#pragma unroll
            for (int g = 0; g < 4; ++g)
                Pl[wid][(lb * 4 + g) * 72 + n * 16 + la] = p1v[n][g];
        __asm__ volatile("s_waitcnt lgkmcnt(0)" ::: "memory");
        __builtin_amdgcn_sched_barrier(0);
        bf16x8 p1a0 = *(const bf16x8*)&Pl[wid][la * 72 + lb * 8];
        bf16x8 p1a1 = *(const bf16x8*)&Pl[wid][la * 72 + 32 + lb * 8];
#pragma unroll
        for (int n = 0; n < 4; ++n)
#pragma unroll
            for (int g = 0; g < 4; ++g)
                Pl[wid][(lb * 4 + g) * 72 + n * 16 + la] = p2v[n][g];
        __asm__ volatile("s_waitcnt lgkmcnt(0)" ::: "memory");
        __builtin_amdgcn_sched_barrier(0);
        bf16x8 p2a0 = *(const bf16x8*)&Pl[wid][la * 72 + lb * 8];
        bf16x8 p2a1 = *(const bf16x8*)&Pl[wid][la * 72 + 32 + lb * 8];

        // mask-frags for Vsum
        bf16x8 p0[2];
#pragma unroll
        for (int f = 0; f < 2; ++f)
#pragma unroll
            for (int jb = 0; jb < 8; ++jb) {
                int c = c0 + 32 * f + lb * 8 + jb;
                bool al = (c == 0) || (c < SEQ && ((c - 1) & 255) <= prA);
                p0[f][jb] = al ? (short)0x3F80 : (short)0;
            }

#pragma unroll
        for (int nd = 0; nd < 4; ++nd) {
            bf16x8 vb0 = *(const bf16x8*)&Vt[(nd * 16 + la) * 72 + lb * 8];
            bf16x8 vb1 = *(const bf16x8*)&Vt[(nd * 16 + la) * 72 + 32 + lb * 8];
            O1[nd] = MFMA(p1a0, vb0, O1[nd]);
            O1[nd] = MFMA(p1a1, vb1, O1[nd]);
            O2[nd] = MFMA(p2a0, vb0, O2[nd]);
            O2[nd] = MFMA(p2a1, vb1, O2[nd]);
            VS[nd] = MFMA(p0[0], vb0, VS[nd]);
            VS[nd] = MFMA(p0[1], vb1, VS[nd]);
        }
    }

    float i1[4], i2g[4], Gl[4];
#pragma unroll
    for (int g = 0; g < 4; ++g) {
        i1[g] = 1.f / d1[g];
        i2g[g] = 1.f / d2[g];
        Gl[g] = gs[g] * i1[g] * (1.f / (float)SEQ) * lam;
    }
    f32x4 outv[4];
#pragma unroll
    for (int nd = 0; nd < 4; ++nd)
#pragma unroll
        for (int g = 0; g < 4; ++g)
            outv[nd][g] = O1[nd][g] * i1[g] - lam * i2g[g] * O2[nd][g] + Gl[g] * VS[nd][g];

    float ssq[4] = {0.f, 0.f, 0.f, 0.f};
#pragma unroll
    for (int nd = 0; nd < 4; ++nd)
#pragma unroll
        for (int g = 0; g < 4; ++g) ssq[g] += outv[nd][g] * outv[nd][g];
#pragma unroll
    for (int off = 1; off < 16; off <<= 1)
#pragma unroll
        for (int g = 0; g < 4; ++g) ssq[g] += __shfl_xor(ssq[g], off);
    float inv[4];
#pragma unroll
    for (int g = 0; g < 4; ++g) inv[g] = rsqrtf(ssq[g] * (1.f / 64.f) + EPS_HEAD);

#pragma unroll
    for (int nd = 0; nd < 4; ++nd) {
        int d = nd * 16 + la;
        float gv = ghead[d];
#pragma unroll
        for (int g = 0; g < 4; ++g) {
            int r = r0w + lb * 4 + g;
            if (r < SEQ)
                attO[(((size_t)b * SEQ + r) * NHEAD + h) * 64 + d] =
                    f2bf(outv[nd][g] * inv[g] * gv);
        }
    }
}

// ---------------------------------------------------------------------------
extern "C" void kernel_launch(void* const* d_in, const int* in_sizes, int n_in,
                              void* d_out, int out_size, void* d_ws, size_t ws_size,
                              hipStream_t stream)
{
    const float* x    = (const float*)d_in[0];
    const float* fcos = (const float*)d_in[2];
    const float* fsin = (const float*)d_in[3];
    const float* Wkvd = (const float*)d_in[4];
    const float* Wqd  = (const float*)d_in[5];
    const float* Wkvu = (const float*)d_in[6];
    const float* Wqu  = (const float*)d_in[7];
    const float* Wo   = (const float*)d_in[8];
    const float* gkv  = (const float*)d_in[9];
    const float* gq   = (const float*)d_in[10];
    const float* gh   = (const float*)d_in[11];
    const float* lq1  = (const float*)d_in[12];
    const float* lk1  = (const float*)d_in[13];
    const float* lq2  = (const float*)d_in[14];
    const float* lk2  = (const float*)d_in[15];
    float* out = (float*)d_out;

    const int R = R_TOT;  // 2050
    char* base = (char*)d_ws;
    size_t off = 0;
    auto alloc = [&](size_t bytes) -> char* {
        char* p = base + off;
        off = (off + bytes + 255) & ~(size_t)255;
        return p;
    };
    const size_t KPL = (size_t)BATCH * NH2 * SEQ * 48 * 2;   // 6,297,600 per plane

    // zoneA: x planes (dead after down-GEMM) -> attO (xh) + Kah (xm..xl)
    unsigned short* xh = (unsigned short*)alloc((size_t)R * 1024 * 2);
    unsigned short* xm = (unsigned short*)alloc((size_t)R * 1024 * 2);
    unsigned short* xl = (unsigned short*)alloc((size_t)R * 1024 * 2);
    unsigned short* attO = xh;                      // R*1024*2 = 4,198,400 fits xh
    unsigned short* Kah  = xm;                      // KPL fits xm+xl (8.4 MB)

    float* ckvqd = (float*)alloc((size_t)R * 672 * 4);
    unsigned short* cnh = (unsigned short*)alloc((size_t)R * 256 * 2);
    unsigned short* cnm = (unsigned short*)alloc((size_t)R * 256 * 2);
    unsigned short* cnl = (unsigned short*)alloc((size_t)R * 256 * 2);
    unsigned short* qnh = (unsigned short*)alloc((size_t)R * 384 * 2);
    unsigned short* qnm = (unsigned short*)alloc((size_t)R * 384 * 2);
    unsigned short* qnl = (unsigned short*)alloc((size_t)R * 384 * 2);
    unsigned short* Kam = (unsigned short*)alloc(KPL);
    unsigned short* Kal = (unsigned short*)alloc(KPL);
    unsigned short* Qah = (unsigned short*)alloc(KPL);
    unsigned short* Qam = (unsigned short*)alloc(KPL);
    unsigned short* Qal = (unsigned short*)alloc(KPL);
    unsigned short* Va  = (unsigned short*)alloc((size_t)BATCH * NHEAD * SEQ * 64 * 2);
    unsigned short* Wdh = (unsigned short*)alloc((size_t)672 * 1024 * 2);
    unsigned short* Wdm = (unsigned short*)alloc((size_t)672 * 1024 * 2);
    unsigned short* Wdl = (unsigned short*)alloc((size_t)672 * 1024 * 2);
    unsigned short* Wuh = (unsigned short*)alloc((size_t)2048 * 256 * 2);
    unsigned short* Wum = (unsigned short*)alloc((size_t)2048 * 256 * 2);
    unsigned short* Wul = (unsigned short*)alloc((size_t)2048 * 256 * 2);
    unsigned short* Wqh = (unsigned short*)alloc((size_t)1536 * 384 * 2);
    unsigned short* Wqm = (unsigned short*)alloc((size_t)1536 * 384 * 2);
    unsigned short* Wql = (unsigned short*)alloc((size_t)1536 * 384 * 2);
    unsigned short* Wo1 = (unsigned short*)alloc((size_t)1024 * 1024 * 2);

    dim3 blk(256);
    conv_x3<<<(R * 1024) / 1024, blk, 0, stream>>>(x, xh, xm, xl, R * 1024);
    conv_wt3<<<dim3(288 / 32, 1024 / 32), blk, 0, stream>>>(Wkvd, Wdh, Wdm, Wdl, 1024, 288);
    conv_wt3<<<dim3(384 / 32, 1024 / 32), blk, 0, stream>>>(Wqd,
        Wdh + (size_t)288 * 1024, Wdm + (size_t)288 * 1024, Wdl + (size_t)288 * 1024, 1024, 384);
    conv_wt3<<<dim3(2048 / 32, 256 / 32), blk, 0, stream>>>(Wkvu, Wuh, Wum, Wul, 256, 2048);
    conv_wt3<<<dim3(1536 / 32, 384 / 32), blk, 0, stream>>>(Wqu, Wqh, Wqm, Wql, 384, 1536);
    conv_wt1<<<dim3(1024 / 32, 1024 / 32), blk, 0, stream>>>(Wo, Wo1, 1024, 1024);

    // down-proj (combined kv|q): C fp32 [R][672]
    gemm3<0><<<dim3(6, 17), blk, 0, stream>>>(xh, xm, xl, Wdh, Wdm, Wdl,
        ckvqd, nullptr, nullptr, nullptr, nullptr, nullptr, nullptr, R, 672, 1024);
    // RMS + split + K-rope
    k_rmsrope3<<<R, blk, 0, stream>>>(ckvqd, cnh, cnm, cnl, qnh, qnm, qnl,
                                      Kah, Kam, Kal, gkv, gq, fcos, fsin);
    // kv-up with fused K/V scatter
    gemm3<1><<<dim3(16, 17), blk, 0, stream>>>(cnh, cnm, cnl, Wuh, Wum, Wul,
        nullptr, Kah, Kam, Kal, Va, nullptr, nullptr, R, 2048, 256);
    // q-up with fused rope/scatter
    gemm3<2><<<dim3(12, 17), blk, 0, stream>>>(qnh, qnm, qnl, Wqh, Wqm, Wql,
        nullptr, Qah, Qam, Qal, nullptr, fcos, fsin, R, 1536, 384);
    // attention
    k_attn3<<<BATCH * NHEAD * 17, blk, 0, stream>>>(Qah, Qam, Qal, Kah, Kam, Kal,
        Va, gh, lq1, lk1, lq2, lk2, attO);
    // output projection (plain bf16)
    gemm1<<<dim3(8, 17), blk, 0, stream>>>(attO, Wo1, out, R, 1024, 1024);
}

// Round 5
// 421.815 us; speedup vs baseline: 3.9360x; 1.5105x over previous
//
#include <hip/hip_runtime.h>
#include <hip/hip_bf16.h>
#include <math.h>

#define NHEAD 16
#define SEQ 1025
#define BATCH 2
#define NH2 32
#define KSCALE (1.0f/48.0f)
#define EPS_RMS 1.1920929e-07f
#define EPS_HEAD 1e-05f
#define LAMBDA_INIT 0.2f
#define R_TOT (BATCH*SEQ)

typedef __attribute__((ext_vector_type(8))) short bf16x8;
typedef __attribute__((ext_vector_type(4))) float f32x4;
typedef __attribute__((ext_vector_type(4))) int  i32x4;

static __device__ __forceinline__ unsigned short f2bf(float x) {
    unsigned int u = __float_as_uint(x);
    unsigned int r = (u + 0x7fffu + ((u >> 16) & 1u)) >> 16;
    return (unsigned short)r;
}
static __device__ __forceinline__ float bf2f(unsigned short h) {
    return __uint_as_float(((unsigned int)h) << 16);
}
static __device__ __forceinline__ void split3(float v, unsigned short& h,
                                              unsigned short& m, unsigned short& l) {
    h = f2bf(v); float r1 = v - bf2f(h);
    m = f2bf(r1); float r2 = r1 - bf2f(m);
    l = f2bf(r2);
}
static __device__ __forceinline__ f32x4 MFMA(bf16x8 a, bf16x8 b, f32x4 c) {
    return __builtin_amdgcn_mfma_f32_16x16x32_bf16(a, b, c, 0, 0, 0);
}

// ---------------------------------------------------------------------------
// x fp32 -> 3-plane bf16
// ---------------------------------------------------------------------------
__global__ __launch_bounds__(256) void conv_x3(const float* __restrict__ x,
    unsigned short* __restrict__ xh, unsigned short* __restrict__ xm,
    unsigned short* __restrict__ xl, int total)
{
    int i = (blockIdx.x * 256 + threadIdx.x) * 4;
    if (i >= total) return;
    f32x4 v = *(const f32x4*)(x + i);
#pragma unroll
    for (int j = 0; j < 4; ++j) {
        unsigned short h, m, l;
        split3(v[j], h, m, l);
        xh[i + j] = h; xm[i + j] = m; xl[i + j] = l;
    }
}

// ---------------------------------------------------------------------------
// W[K,N] fp32 -> 3-plane bf16 transposed [N,K]
// ---------------------------------------------------------------------------
__global__ __launch_bounds__(256) void conv_wt3(const float* __restrict__ W,
    unsigned short* __restrict__ Th, unsigned short* __restrict__ Tm,
    unsigned short* __restrict__ Tl, int K, int N)
{
    __shared__ float tile[32][33];
    int n0 = blockIdx.x * 32, k0 = blockIdx.y * 32;
    int tx = threadIdx.x & 31, ty = threadIdx.x >> 5;
    for (int kk = ty; kk < 32; kk += 8) {
        int k = k0 + kk, n = n0 + tx;
        tile[kk][tx] = (k < K && n < N) ? W[(size_t)k * N + n] : 0.f;
    }
    __syncthreads();
    for (int nn = ty; nn < 32; nn += 8) {
        int n = n0 + nn, k = k0 + tx;
        if (n < N && k < K) {
            unsigned short h, m, l;
            split3(tile[tx][nn], h, m, l);
            Th[(size_t)n * K + k] = h;
            Tm[(size_t)n * K + k] = m;
            Tl[(size_t)n * K + k] = l;
        }
    }
}

// single-plane transpose-convert (for W_o)
__global__ __launch_bounds__(256) void conv_wt1(const float* __restrict__ W,
    unsigned short* __restrict__ Th, int K, int N)
{
    __shared__ float tile[32][33];
    int n0 = blockIdx.x * 32, k0 = blockIdx.y * 32;
    int tx = threadIdx.x & 31, ty = threadIdx.x >> 5;
    for (int kk = ty; kk < 32; kk += 8) {
        int k = k0 + kk, n = n0 + tx;
        tile[kk][tx] = (k < K && n < N) ? W[(size_t)k * N + n] : 0.f;
    }
    __syncthreads();
    for (int nn = ty; nn < 32; nn += 8) {
        int n = n0 + nn, k = k0 + tx;
        if (n < N && k < K) Th[(size_t)n * K + k] = f2bf(tile[tx][nn]);
    }
}

// ---------------------------------------------------------------------------
// 3-way split MFMA GEMM:  C = A @ B^T  (B transposed [N,K]), 6 products
// (hh, hm, mh, hl, mm, lh) -> ~2^-24 relative accuracy.
// EPI=0: plain fp32 C.  EPI=1: kv-up scatter (K 3-plane + V bf16).
// EPI=2: q-up scatter (rope via lane-pair shfl, KSCALE, Q 3-plane).
// ---------------------------------------------------------------------------
template<int EPI>
__global__ __launch_bounds__(256) void gemm3(
    const unsigned short* __restrict__ Ah, const unsigned short* __restrict__ Am,
    const unsigned short* __restrict__ Al,
    const unsigned short* __restrict__ Bh, const unsigned short* __restrict__ Bm,
    const unsigned short* __restrict__ Bl,
    float* __restrict__ C,
    unsigned short* __restrict__ D0, unsigned short* __restrict__ D1,
    unsigned short* __restrict__ D2, unsigned short* __restrict__ D3,
    const float* __restrict__ fcos, const float* __restrict__ fsin,
    int M, int N, int K)
{
    __shared__ unsigned short LA[3][128 * 40];
    __shared__ unsigned short LB[3][128 * 40];

    int tid = threadIdx.x;
    int wid = tid >> 6, lane = tid & 63;
    int la = lane & 15, lb = lane >> 4;
    int bm = blockIdx.y * 128, bn = blockIdx.x * 128;
    int wr = (wid >> 1) * 64, wc = (wid & 1) * 64;

    const unsigned short* APl[3] = {Ah, Am, Al};
    const unsigned short* BPl[3] = {Bh, Bm, Bl};

    f32x4 acc[4][4];
#pragma unroll
    for (int m = 0; m < 4; ++m)
#pragma unroll
        for (int n = 0; n < 4; ++n) acc[m][n] = (f32x4){0.f, 0.f, 0.f, 0.f};

    for (int k0 = 0; k0 < K; k0 += 32) {
        __syncthreads();
#pragma unroll
        for (int p = 0; p < 3; ++p) {
#pragma unroll
            for (int i0 = 0; i0 < 2; ++i0) {
                int i = tid + i0 * 256;
                int row = i >> 2, ko = (i & 3) * 8;
                i32x4 z = {0, 0, 0, 0};
                i32x4 v = z, w = z;
                int gr = bm + row;
                if (gr < M) v = *(const i32x4*)(APl[p] + (size_t)gr * K + k0 + ko);
                *(i32x4*)&LA[p][row * 40 + ko] = v;
                int gn = bn + row;
                if (gn < N) w = *(const i32x4*)(BPl[p] + (size_t)gn * K + k0 + ko);
                *(i32x4*)&LB[p][row * 40 + ko] = w;
            }
        }
        __syncthreads();
        bf16x8 a_[3][4], b_[3][4];
#pragma unroll
        for (int p = 0; p < 3; ++p) {
#pragma unroll
            for (int m = 0; m < 4; ++m)
                a_[p][m] = *(const bf16x8*)&LA[p][(wr + m * 16 + la) * 40 + lb * 8];
#pragma unroll
            for (int n = 0; n < 4; ++n)
                b_[p][n] = *(const bf16x8*)&LB[p][(wc + n * 16 + la) * 40 + lb * 8];
        }
#pragma unroll
        for (int m = 0; m < 4; ++m)
#pragma unroll
            for (int n = 0; n < 4; ++n) {
                acc[m][n] = MFMA(a_[0][m], b_[0][n], acc[m][n]);
                acc[m][n] = MFMA(a_[0][m], b_[1][n], acc[m][n]);
                acc[m][n] = MFMA(a_[1][m], b_[0][n], acc[m][n]);
                acc[m][n] = MFMA(a_[0][m], b_[2][n], acc[m][n]);
                acc[m][n] = MFMA(a_[1][m], b_[1][n], acc[m][n]);
                acc[m][n] = MFMA(a_[2][m], b_[0][n], acc[m][n]);
            }
    }

#pragma unroll
    for (int m = 0; m < 4; ++m)
#pragma unroll
        for (int n = 0; n < 4; ++n) {
            int gc = bn + wc + n * 16 + la;
#pragma unroll
            for (int r = 0; r < 4; ++r) {
                int gr = bm + wr + m * 16 + lb * 4 + r;
                float v = acc[m][n][r];
                if (EPI == 0) {
                    if (gr < M && gc < N) C[(size_t)gr * N + gc] = v;
                } else if (EPI == 1) {
                    if (gr < M) {
                        int b = gr / SEQ, s = gr - b * SEQ;
                        int h2 = gc >> 7, rem = gc & 127;
                        if (rem < 64) {
                            int H = 2 * h2 + (rem >> 5), d = rem & 31;
                            size_t idx = (((size_t)b * NH2 + H) * SEQ + s) * 48 + d;
                            unsigned short hh, mm2, ll;
                            split3(v, hh, mm2, ll);
                            D0[idx] = hh; D1[idx] = mm2; D2[idx] = ll;
                        } else {
                            D3[(((size_t)b * NHEAD + h2) * SEQ + s) * 64 + (rem - 64)] = f2bf(v);
                        }
                    }
                } else {
                    // EPI == 2: q scatter with rope. shfl BEFORE any guard.
                    float pv = __shfl_xor(v, 1);
                    if (gr < M) {
                        int b = gr / SEQ, s = gr - b * SEQ;
                        int h2 = gc / 96, rem = gc - h2 * 96;
                        int H, d; float outv;
                        if (rem < 64) {
                            H = 2 * h2 + (rem >> 5); d = rem & 31; outv = v;
                        } else {
                            int dd = rem - 64;
                            int e = dd >> 4, j = (dd & 15) >> 1;
                            H = 2 * h2 + e; d = 32 + (dd & 15);
                            if (s != 0) {
                                int p = (s - 1) & 255;
                                float cc = fcos[p * 8 + j], sn = fsin[p * 8 + j];
                                outv = ((la & 1) == 0) ? (v * cc - pv * sn)
                                                       : (pv * sn + v * cc);
                            } else outv = v;
                        }
                        outv *= KSCALE;
                        size_t idx = (((size_t)b * NH2 + H) * SEQ + s) * 48 + d;
                        unsigned short hh, mm2, ll;
                        split3(outv, hh, mm2, ll);
                        D0[idx] = hh; D1[idx] = mm2; D2[idx] = ll;
                    }
                }
            }
        }
}

// ---------------------------------------------------------------------------
// 1-plane bf16 GEMM for the output projection.
// ---------------------------------------------------------------------------
__global__ __launch_bounds__(256) void gemm1(
    const unsigned short* __restrict__ Ah, const unsigned short* __restrict__ Bh,
    float* __restrict__ C, int M, int N, int K)
{
    __shared__ unsigned short As[128 * 40];
    __shared__ unsigned short Bs[128 * 40];
    int tid = threadIdx.x;
    int wid = tid >> 6, lane = tid & 63;
    int la = lane & 15, lb = lane >> 4;
    int bm = blockIdx.y * 128, bn = blockIdx.x * 128;
    int wr = (wid >> 1) * 64, wc = (wid & 1) * 64;
    f32x4 acc[4][4];
#pragma unroll
    for (int m = 0; m < 4; ++m)
#pragma unroll
        for (int n = 0; n < 4; ++n) acc[m][n] = (f32x4){0.f, 0.f, 0.f, 0.f};
    for (int k0 = 0; k0 < K; k0 += 32) {
        __syncthreads();
#pragma unroll
        for (int i0 = 0; i0 < 2; ++i0) {
            int i = tid + i0 * 256;
            int row = i >> 2, ko = (i & 3) * 8;
            i32x4 z = {0, 0, 0, 0};
            i32x4 v = z, w = z;
            int gr = bm + row;
            if (gr < M) v = *(const i32x4*)(Ah + (size_t)gr * K + k0 + ko);
            *(i32x4*)&As[row * 40 + ko] = v;
            int gn = bn + row;
            if (gn < N) w = *(const i32x4*)(Bh + (size_t)gn * K + k0 + ko);
            *(i32x4*)&Bs[row * 40 + ko] = w;
        }
        __syncthreads();
        bf16x8 a_[4], b_[4];
#pragma unroll
        for (int m = 0; m < 4; ++m) a_[m] = *(const bf16x8*)&As[(wr + m * 16 + la) * 40 + lb * 8];
#pragma unroll
        for (int n = 0; n < 4; ++n) b_[n] = *(const bf16x8*)&Bs[(wc + n * 16 + la) * 40 + lb * 8];
#pragma unroll
        for (int m = 0; m < 4; ++m)
#pragma unroll
            for (int n = 0; n < 4; ++n) acc[m][n] = MFMA(a_[m], b_[n], acc[m][n]);
    }
#pragma unroll
    for (int m = 0; m < 4; ++m)
#pragma unroll
        for (int n = 0; n < 4; ++n) {
            int gc = bn + wc + n * 16 + la;
            if (gc >= N) continue;
#pragma unroll
            for (int r = 0; r < 4; ++r) {
                int gr = bm + wr + m * 16 + lb * 4 + r;
                if (gr < M) C[(size_t)gr * N + gc] = acc[m][n][r];
            }
        }
}

// ---------------------------------------------------------------------------
// RMS-norm both streams + write K-rope dims (3-plane) directly.
// ckvqd: [R][672] fp32 (0..255 ckv | 256..287 rope | 288..671 qd)
// ---------------------------------------------------------------------------
__global__ __launch_bounds__(256) void k_rmsrope3(
    const float* __restrict__ ckvqd,
    unsigned short* __restrict__ cnh, unsigned short* __restrict__ cnm,
    unsigned short* __restrict__ cnl,
    unsigned short* __restrict__ qnh, unsigned short* __restrict__ qnm,
    unsigned short* __restrict__ qnl,
    unsigned short* __restrict__ Kah, unsigned short* __restrict__ Kam,
    unsigned short* __restrict__ Kal,
    const float* __restrict__ gkv, const float* __restrict__ gq,
    const float* __restrict__ fcos, const float* __restrict__ fsin)
{
    __shared__ float red[256];
    __shared__ float rot[32];
    int row = blockIdx.x, tid = threadIdx.x;
    int b = row / SEQ, s = row - b * SEQ;
    const float* cp = ckvqd + (size_t)row * 672;
    float c0 = cp[tid];
    float q0 = cp[288 + tid];
    float q1 = (tid < 128) ? cp[544 + tid] : 0.f;

    red[tid] = c0 * c0;
    __syncthreads();
    for (int o = 128; o; o >>= 1) { if (tid < o) red[tid] += red[tid + o]; __syncthreads(); }
    float inv1 = rsqrtf(red[0] * (1.f / 256.f) + EPS_RMS);
    __syncthreads();
    red[tid] = q0 * q0 + q1 * q1;
    __syncthreads();
    for (int o = 128; o; o >>= 1) { if (tid < o) red[tid] += red[tid + o]; __syncthreads(); }
    float inv2 = rsqrtf(red[0] * (1.f / 384.f) + EPS_RMS);

    unsigned short h, m, l;
    split3(c0 * inv1 * gkv[tid], h, m, l);
    size_t ci = (size_t)row * 256 + tid;
    cnh[ci] = h; cnm[ci] = m; cnl[ci] = l;

    split3(q0 * inv2 * gq[tid], h, m, l);
    size_t qi = (size_t)row * 384 + tid;
    qnh[qi] = h; qnm[qi] = m; qnl[qi] = l;
    if (tid < 128) {
        split3(q1 * inv2 * gq[256 + tid], h, m, l);
        qnh[qi + 256] = h; qnm[qi + 256] = m; qnl[qi + 256] = l;
    }

    if (tid < 16) {  // rotate rope pairs (16 pairs of the 32-dim rope vec)
        float r0 = cp[256 + 2 * tid], r1 = cp[256 + 2 * tid + 1];
        float o0, o1;
        if (s == 0) { o0 = r0; o1 = r1; }
        else {
            int p = (s - 1) & 255;
            int j = tid & 7;
            float cc = fcos[p * 8 + j], sn = fsin[p * 8 + j];
            o0 = r0 * cc - r1 * sn;
            o1 = r0 * sn + r1 * cc;
        }
        rot[2 * tid] = o0; rot[2 * tid + 1] = o1;
    }
    __syncthreads();
    for (int t = tid; t < 512; t += 256) {   // 32 heads x 16 dims
        int H = t >> 4, dd = t & 15;
        int e = H & 1;
        split3(rot[e * 16 + dd], h, m, l);
        size_t idx = (((size_t)b * NH2 + H) * SEQ + s) * 48 + 32 + dd;
        Kah[idx] = h; Kam[idx] = m; Kal[idx] = l;
    }
}

// ---------------------------------------------------------------------------
// MFMA cog-attention v4:
//  - no-max signed softmax (|S| bounded => exp safe): no per-tile reductions,
//    no rescales; row sums accumulated per-lane, reduced once at the end
//  - all 6 K planes + V staged in ONE phase; 2 barriers/tile
//  - register prefetch of the next needed tile overlaps global latency
//  - XCD-aware bijective block swizzle (544 = 8*68)
// ---------------------------------------------------------------------------
__global__ __launch_bounds__(256, 2) void k_attn4(
    const unsigned short* __restrict__ Qah, const unsigned short* __restrict__ Qam,
    const unsigned short* __restrict__ Qal,
    const unsigned short* __restrict__ Kah, const unsigned short* __restrict__ Kam,
    const unsigned short* __restrict__ Kal,
    const unsigned short* __restrict__ Va, const float* __restrict__ ghead,
    const float* __restrict__ lq1, const float* __restrict__ lk1,
    const float* __restrict__ lq2, const float* __restrict__ lk2,
    unsigned short* __restrict__ attO)
{
    __shared__ unsigned short KS[6][64 * 72];   // planes 0..2: K1 h/m/l, 3..5: K2 h/m/l
    __shared__ unsigned short Vt[64 * 72];
    __shared__ unsigned short Pl[4][16 * 72];

    int bid0 = blockIdx.x;
    int bid = (bid0 & 7) * 68 + (bid0 >> 3);   // XCD swizzle, bijective (544=8*68)
    int rt = bid % 17;
    int bh = bid / 17;
    int h = bh & 15, b = bh >> 4;
    int tid = threadIdx.x, wid = tid >> 6, lane = tid & 63;
    int la = lane & 15, lb = lane >> 4;
    int r0 = rt * 64, r0w = r0 + wid * 16;

    float e1 = 0.f, e2 = 0.f;
    for (int i = 0; i < 32; ++i) { e1 = fmaf(lq1[i], lk1[i], e1); e2 = fmaf(lq2[i], lk2[i], e2); }
    float lam = __expf(e1) - __expf(e2) + LAMBDA_INIT;

    int pr[4];
#pragma unroll
    for (int g = 0; g < 4; ++g) {
        int r = r0w + lb * 4 + g;
        pr[g] = (r >= 1 && r < SEQ) ? ((r - 1) & 255) : -1;
    }
    int rA = r0w + la;
    int prA = (rA >= 1 && rA < SEQ) ? ((rA - 1) & 255) : -1;

    int prm = -1;
    for (int i = 0; i < 64; ++i) {
        int r = r0 + i;
        if (r >= 1 && r < SEQ) { int p = (r - 1) & 255; prm = p > prm ? p : prm; }
    }

    const size_t hb1 = ((size_t)(b * NH2 + 2 * h)) * SEQ * 48;
    const size_t hb2 = ((size_t)(b * NH2 + 2 * h + 1)) * SEQ * 48;
    const unsigned short* vp = Va + ((size_t)(b * NHEAD + h)) * SEQ * 64;
    const unsigned short* KP[6] = {Kah + hb1, Kam + hb1, Kal + hb1,
                                   Kah + hb2, Kam + hb2, Kal + hb2};

    // q fragments (3 planes x 2 k-halves, both streams)
    int qrow = r0w + la; if (qrow > SEQ - 1) qrow = SEQ - 1;
    bf16x8 zf;
#pragma unroll
    for (int u = 0; u < 8; ++u) zf[u] = 0;
    bf16x8 q1[3][2], q2[3][2];
    {
        const unsigned short* QPl[3] = {Qah, Qam, Qal};
#pragma unroll
        for (int p = 0; p < 3; ++p)
#pragma unroll
            for (int f = 0; f < 2; ++f) {
                if (f == 0 || lb < 2) {
                    q1[p][f] = *(const bf16x8*)(QPl[p] + hb1 + (size_t)qrow * 48 + 32 * f + lb * 8);
                    q2[p][f] = *(const bf16x8*)(QPl[p] + hb2 + (size_t)qrow * 48 + 32 * f + lb * 8);
                } else { q1[p][f] = zf; q2[p][f] = zf; }
            }
    }

    // zero the pad region (shorts 48..63 of each KS row) ONCE
    {
        i32x4 z4 = {0, 0, 0, 0};
        for (int t = tid; t < 768; t += 256) {
            int plane = t >> 7, rr = (t & 127) >> 1, hf = t & 1;
            *(i32x4*)&KS[plane][rr * 72 + 48 + hf * 8] = z4;
        }
    }

    // prefetch registers
    i32x4 pre[6][2], vv[2];
    auto LOADT = [&](int c0n) {
#pragma unroll
        for (int p = 0; p < 6; ++p)
#pragma unroll
            for (int it = 0; it < 2; ++it) {
                int i = tid + it * 256;
                int c = i >> 3, u = i & 7;
                int gc = c0n + c; if (gc > SEQ - 1) gc = SEQ - 1;
                i32x4 v = {0, 0, 0, 0};
                if (u < 6) v = *(const i32x4*)(KP[p] + (size_t)gc * 48 + u * 8);
                pre[p][it] = v;
            }
#pragma unroll
        for (int it = 0; it < 2; ++it) {
            int i = tid + it * 256;
            int c = i >> 3, ko = (i & 7) * 8;
            int gc = c0n + c; if (gc > SEQ - 1) gc = SEQ - 1;
            vv[it] = *(const i32x4*)(vp + (size_t)gc * 64 + ko);
        }
    };
    auto WRITET = [&]() {
#pragma unroll
        for (int p = 0; p < 6; ++p)
#pragma unroll
            for (int it = 0; it < 2; ++it) {
                int i = tid + it * 256;
                int c = i >> 3, u = i & 7;
                if (u < 6) *(i32x4*)&KS[p][c * 72 + u * 8] = pre[p][it];
            }
#pragma unroll
        for (int it = 0; it < 2; ++it) {
            int i = tid + it * 256;
            int c = i >> 3, ko = (i & 7) * 8;
            unsigned short tmp[8];
            *(i32x4*)tmp = vv[it];
#pragma unroll
            for (int u = 0; u < 8; ++u) Vt[(ko + u) * 72 + c] = tmp[u];
        }
    };

    // accumulators
    f32x4 O1[4], O2[4], VS[4];
#pragma unroll
    for (int nd = 0; nd < 4; ++nd) {
        O1[nd] = (f32x4){0.f, 0.f, 0.f, 0.f};
        O2[nd] = (f32x4){0.f, 0.f, 0.f, 0.f};
        VS[nd] = (f32x4){0.f, 0.f, 0.f, 0.f};
    }
    float dA1[4] = {0.f, 0.f, 0.f, 0.f}, dA2[4] = {0.f, 0.f, 0.f, 0.f};
    float gsA[4] = {0.f, 0.f, 0.f, 0.f};
    f32x4 z = (f32x4){0.f, 0.f, 0.f, 0.f};

    // prologue: stage tile 0 (always needed)
    LOADT(0);
    WRITET();
    __syncthreads();

    for (int j = 0; j <= 16; ++j) {
        bool need = (j == 16) ? (prm >= 255)
                              : (((j & 3) == 0) || (prm >= 64 * (j & 3) - 1));
        if (!need) continue;
        int c0 = j * 64;

        // find next needed tile; issue its loads now (hidden under compute)
        int nj = -1;
        for (int t2 = j + 1; t2 <= 16; ++t2) {
            bool nd2 = (t2 == 16) ? (prm >= 255)
                                  : (((t2 & 3) == 0) || (prm >= 64 * (t2 & 3) - 1));
            if (nd2) { nj = t2; break; }
        }
        if (nj >= 0) LOADT(nj * 64);

        // ---- scores S1 (K1 = planes 0..2) ----
        f32x4 s1[4], s2[4];
#pragma unroll
        for (int n = 0; n < 4; ++n) {
            int ro = (n * 16 + la) * 72;
            bf16x8 kh0 = *(const bf16x8*)&KS[0][ro + lb * 8];
            bf16x8 kh1 = *(const bf16x8*)&KS[0][ro + 32 + lb * 8];
            bf16x8 km0 = *(const bf16x8*)&KS[1][ro + lb * 8];
            bf16x8 km1 = *(const bf16x8*)&KS[1][ro + 32 + lb * 8];
            bf16x8 kl0 = *(const bf16x8*)&KS[2][ro + lb * 8];
            bf16x8 kl1 = *(const bf16x8*)&KS[2][ro + 32 + lb * 8];
            f32x4 s = z;
            s = MFMA(q1[0][0], kh0, s); s = MFMA(q1[0][1], kh1, s);
            s = MFMA(q1[0][0], km0, s); s = MFMA(q1[0][1], km1, s);
            s = MFMA(q1[1][0], kh0, s); s = MFMA(q1[1][1], kh1, s);
            s = MFMA(q1[0][0], kl0, s); s = MFMA(q1[0][1], kl1, s);
            s = MFMA(q1[1][0], km0, s); s = MFMA(q1[1][1], km1, s);
            s = MFMA(q1[2][0], kh0, s); s = MFMA(q1[2][1], kh1, s);
            s1[n] = s;
        }
        // ---- scores S2 (K2 = planes 3..5) ----
#pragma unroll
        for (int n = 0; n < 4; ++n) {
            int ro = (n * 16 + la) * 72;
            bf16x8 kh0 = *(const bf16x8*)&KS[3][ro + lb * 8];
            bf16x8 kh1 = *(const bf16x8*)&KS[3][ro + 32 + lb * 8];
            bf16x8 km0 = *(const bf16x8*)&KS[4][ro + lb * 8];
            bf16x8 km1 = *(const bf16x8*)&KS[4][ro + 32 + lb * 8];
            bf16x8 kl0 = *(const bf16x8*)&KS[5][ro + lb * 8];
            bf16x8 kl1 = *(const bf16x8*)&KS[5][ro + 32 + lb * 8];
            f32x4 s = z;
            s = MFMA(q2[0][0], kh0, s); s = MFMA(q2[0][1], kh1, s);
            s = MFMA(q2[0][0], km0, s); s = MFMA(q2[0][1], km1, s);
            s = MFMA(q2[1][0], kh0, s); s = MFMA(q2[1][1], kh1, s);
            s = MFMA(q2[0][0], kl0, s); s = MFMA(q2[0][1], kl1, s);
            s = MFMA(q2[1][0], km0, s); s = MFMA(q2[1][1], km1, s);
            s = MFMA(q2[2][0], kh0, s); s = MFMA(q2[2][1], kh1, s);
            s2[n] = s;
        }

        // ---- no-max signed softmax terms + per-lane sum accumulation ----
        unsigned short p1v[4][4], p2v[4][4];
#pragma unroll
        for (int n = 0; n < 4; ++n) {
            int c = c0 + n * 16 + la;
            int cm = (c - 1) & 255;
            bool cin = (c < SEQ);
#pragma unroll
            for (int g = 0; g < 4; ++g) {
                bool al = (c == 0) || (cin && cm <= pr[g]);
                float a = s1[n][g];
                float pa = __expf(fabsf(a));
                float sa = (a > 0.f) ? pa : ((a < 0.f) ? -pa : 0.f);
                if (al) { dA1[g] += pa; gsA[g] += sa; p1v[n][g] = f2bf(sa); }
                else p1v[n][g] = 0;
                float bb = s2[n][g];
                float pb = __expf(fabsf(bb));
                float sb = (bb > 0.f) ? pb : ((bb < 0.f) ? -pb : 0.f);
                if (al) { dA2[g] += pb; p2v[n][g] = f2bf(sb); }
                else p2v[n][g] = 0;
            }
        }

        // ---- P1 -> A-frags via wave-private LDS ----
#pragma unroll
        for (int n = 0; n < 4; ++n)
#pragma unroll
            for (int g = 0; g < 4; ++g)
                Pl[wid][(lb * 4 + g) * 72 + n * 16 + la] = p1v[n][g];
        __asm__ volatile("s_waitcnt lgkmcnt(0)" ::: "memory");
        __builtin_amdgcn_sched_barrier(0);
        bf16x8 p1a0 = *(const bf16x8*)&Pl[wid][la * 72 + lb * 8];
        bf16x8 p1a1 = *(const bf16x8*)&Pl[wid][la * 72 + 32 + lb * 8];
#pragma unroll
        for (int n = 0; n < 4; ++n)
#pragma unroll
            for (int g = 0; g < 4; ++g)
                Pl[wid][(lb * 4 + g) * 72 + n * 16 + la] = p2v[n][g];
        __asm__ volatile("s_waitcnt lgkmcnt(0)" ::: "memory");
        __builtin_amdgcn_sched_barrier(0);
        bf16x8 p2a0 = *(const bf16x8*)&Pl[wid][la * 72 + lb * 8];
        bf16x8 p2a1 = *(const bf16x8*)&Pl[wid][la * 72 + 32 + lb * 8];

        // mask-frags for Vsum
        bf16x8 p0[2];
#pragma unroll
        for (int f = 0; f < 2; ++f)
#pragma unroll
            for (int jb = 0; jb < 8; ++jb) {
                int c = c0 + 32 * f + lb * 8 + jb;
                bool al = (c == 0) || (c < SEQ && ((c - 1) & 255) <= prA);
                p0[f][jb] = al ? (short)0x3F80 : (short)0;
            }

        // ---- PV + VS ----
#pragma unroll
        for (int nd = 0; nd < 4; ++nd) {
            int ro = (nd * 16 + la) * 72;
            bf16x8 vb0 = *(const bf16x8*)&Vt[ro + lb * 8];
            bf16x8 vb1 = *(const bf16x8*)&Vt[ro + 32 + lb * 8];
            O1[nd] = MFMA(p1a0, vb0, O1[nd]);
            O1[nd] = MFMA(p1a1, vb1, O1[nd]);
            O2[nd] = MFMA(p2a0, vb0, O2[nd]);
            O2[nd] = MFMA(p2a1, vb1, O2[nd]);
            VS[nd] = MFMA(p0[0], vb0, VS[nd]);
            VS[nd] = MFMA(p0[1], vb1, VS[nd]);
        }

        // ---- publish prefetched tile ----
        if (nj >= 0) {
            __syncthreads();   // everyone done reading tile j
            WRITET();
            __syncthreads();   // tile nj visible
        }
    }

    // ---- final row-sum reductions (once, not per tile) ----
#pragma unroll
    for (int off = 1; off < 16; off <<= 1) {
#pragma unroll
        for (int g = 0; g < 4; ++g) {
            dA1[g] += __shfl_xor(dA1[g], off);
            dA2[g] += __shfl_xor(dA2[g], off);
            gsA[g] += __shfl_xor(gsA[g], off);
        }
    }

    float i1[4], i2g[4], Gl[4];
#pragma unroll
    for (int g = 0; g < 4; ++g) {
        i1[g] = 1.f / dA1[g];
        i2g[g] = 1.f / dA2[g];
        Gl[g] = gsA[g] * i1[g] * (1.f / (float)SEQ) * lam;
    }
    f32x4 outv[4];
#pragma unroll
    for (int nd = 0; nd < 4; ++nd)
#pragma unroll
        for (int g = 0; g < 4; ++g)
            outv[nd][g] = O1[nd][g] * i1[g] - lam * i2g[g] * O2[nd][g] + Gl[g] * VS[nd][g];

    float ssq[4] = {0.f, 0.f, 0.f, 0.f};
#pragma unroll
    for (int nd = 0; nd < 4; ++nd)
#pragma unroll
        for (int g = 0; g < 4; ++g) ssq[g] += outv[nd][g] * outv[nd][g];
#pragma unroll
    for (int off = 1; off < 16; off <<= 1)
#pragma unroll
        for (int g = 0; g < 4; ++g) ssq[g] += __shfl_xor(ssq[g], off);
    float inv[4];
#pragma unroll
    for (int g = 0; g < 4; ++g) inv[g] = rsqrtf(ssq[g] * (1.f / 64.f) + EPS_HEAD);

#pragma unroll
    for (int nd = 0; nd < 4; ++nd) {
        int d = nd * 16 + la;
        float gv = ghead[d];
#pragma unroll
        for (int g = 0; g < 4; ++g) {
            int r = r0w + lb * 4 + g;
            if (r < SEQ)
                attO[(((size_t)b * SEQ + r) * NHEAD + h) * 64 + d] =
                    f2bf(outv[nd][g] * inv[g] * gv);
        }
    }
}

// ---------------------------------------------------------------------------
extern "C" void kernel_launch(void* const* d_in, const int* in_sizes, int n_in,
                              void* d_out, int out_size, void* d_ws, size_t ws_size,
                              hipStream_t stream)
{
    const float* x    = (const float*)d_in[0];
    const float* fcos = (const float*)d_in[2];
    const float* fsin = (const float*)d_in[3];
    const float* Wkvd = (const float*)d_in[4];
    const float* Wqd  = (const float*)d_in[5];
    const float* Wkvu = (const float*)d_in[6];
    const float* Wqu  = (const float*)d_in[7];
    const float* Wo   = (const float*)d_in[8];
    const float* gkv  = (const float*)d_in[9];
    const float* gq   = (const float*)d_in[10];
    const float* gh   = (const float*)d_in[11];
    const float* lq1  = (const float*)d_in[12];
    const float* lk1  = (const float*)d_in[13];
    const float* lq2  = (const float*)d_in[14];
    const float* lk2  = (const float*)d_in[15];
    float* out = (float*)d_out;

    const int R = R_TOT;  // 2050
    char* base = (char*)d_ws;
    size_t off = 0;
    auto alloc = [&](size_t bytes) -> char* {
        char* p = base + off;
        off = (off + bytes + 255) & ~(size_t)255;
        return p;
    };
    const size_t KPL = (size_t)BATCH * NH2 * SEQ * 48 * 2;   // 6,297,600 per plane

    // zoneA: x planes (dead after down-GEMM) -> attO (xh) + Kah (xm..xl)
    unsigned short* xh = (unsigned short*)alloc((size_t)R * 1024 * 2);
    unsigned short* xm = (unsigned short*)alloc((size_t)R * 1024 * 2);
    unsigned short* xl = (unsigned short*)alloc((size_t)R * 1024 * 2);
    unsigned short* attO = xh;                      // R*1024*2 = 4,198,400 fits xh
    unsigned short* Kah  = xm;                      // KPL fits xm+xl (8.4 MB)

    float* ckvqd = (float*)alloc((size_t)R * 672 * 4);
    unsigned short* cnh = (unsigned short*)alloc((size_t)R * 256 * 2);
    unsigned short* cnm = (unsigned short*)alloc((size_t)R * 256 * 2);
    unsigned short* cnl = (unsigned short*)alloc((size_t)R * 256 * 2);
    unsigned short* qnh = (unsigned short*)alloc((size_t)R * 384 * 2);
    unsigned short* qnm = (unsigned short*)alloc((size_t)R * 384 * 2);
    unsigned short* qnl = (unsigned short*)alloc((size_t)R * 384 * 2);
    unsigned short* Kam = (unsigned short*)alloc(KPL);
    unsigned short* Kal = (unsigned short*)alloc(KPL);
    unsigned short* Qah = (unsigned short*)alloc(KPL);
    unsigned short* Qam = (unsigned short*)alloc(KPL);
    unsigned short* Qal = (unsigned short*)alloc(KPL);
    unsigned short* Va  = (unsigned short*)alloc((size_t)BATCH * NHEAD * SEQ * 64 * 2);
    unsigned short* Wdh = (unsigned short*)alloc((size_t)672 * 1024 * 2);
    unsigned short* Wdm = (unsigned short*)alloc((size_t)672 * 1024 * 2);
    unsigned short* Wdl = (unsigned short*)alloc((size_t)672 * 1024 * 2);
    unsigned short* Wuh = (unsigned short*)alloc((size_t)2048 * 256 * 2);
    unsigned short* Wum = (unsigned short*)alloc((size_t)2048 * 256 * 2);
    unsigned short* Wul = (unsigned short*)alloc((size_t)2048 * 256 * 2);
    unsigned short* Wqh = (unsigned short*)alloc((size_t)1536 * 384 * 2);
    unsigned short* Wqm = (unsigned short*)alloc((size_t)1536 * 384 * 2);
    unsigned short* Wql = (unsigned short*)alloc((size_t)1536 * 384 * 2);
    unsigned short* Wo1 = (unsigned short*)alloc((size_t)1024 * 1024 * 2);

    dim3 blk(256);
    conv_x3<<<(R * 1024) / 1024, blk, 0, stream>>>(x, xh, xm, xl, R * 1024);
    conv_wt3<<<dim3(288 / 32, 1024 / 32), blk, 0, stream>>>(Wkvd, Wdh, Wdm, Wdl, 1024, 288);
    conv_wt3<<<dim3(384 / 32, 1024 / 32), blk, 0, stream>>>(Wqd,
        Wdh + (size_t)288 * 1024, Wdm + (size_t)288 * 1024, Wdl + (size_t)288 * 1024, 1024, 384);
    conv_wt3<<<dim3(2048 / 32, 256 / 32), blk, 0, stream>>>(Wkvu, Wuh, Wum, Wul, 256, 2048);
    conv_wt3<<<dim3(1536 / 32, 384 / 32), blk, 0, stream>>>(Wqu, Wqh, Wqm, Wql, 384, 1536);
    conv_wt1<<<dim3(1024 / 32, 1024 / 32), blk, 0, stream>>>(Wo, Wo1, 1024, 1024);

    // down-proj (combined kv|q): C fp32 [R][672]
    gemm3<0><<<dim3(6, 17), blk, 0, stream>>>(xh, xm, xl, Wdh, Wdm, Wdl,
        ckvqd, nullptr, nullptr, nullptr, nullptr, nullptr, nullptr, R, 672, 1024);
    // RMS + split + K-rope
    k_rmsrope3<<<R, blk, 0, stream>>>(ckvqd, cnh, cnm, cnl, qnh, qnm, qnl,
                                      Kah, Kam, Kal, gkv, gq, fcos, fsin);
    // kv-up with fused K/V scatter
    gemm3<1><<<dim3(16, 17), blk, 0, stream>>>(cnh, cnm, cnl, Wuh, Wum, Wul,
        nullptr, Kah, Kam, Kal, Va, nullptr, nullptr, R, 2048, 256);
    // q-up with fused rope/scatter
    gemm3<2><<<dim3(12, 17), blk, 0, stream>>>(qnh, qnm, qnl, Wqh, Wqm, Wql,
        nullptr, Qah, Qam, Qal, nullptr, fcos, fsin, R, 1536, 384);
    // attention
    k_attn4<<<BATCH * NHEAD * 17, blk, 0, stream>>>(Qah, Qam, Qal, Kah, Kam, Kal,
        Va, gh, lq1, lk1, lq2, lk2, attO);
    // output projection (plain bf16)
    gemm1<<<dim3(8, 17), blk, 0, stream>>>(attO, Wo1, out, R, 1024, 1024);
}

// Round 6
// 375.601 us; speedup vs baseline: 4.4203x; 1.1230x over previous
//
#include <hip/hip_runtime.h>
#include <hip/hip_bf16.h>
#include <math.h>

#define NHEAD 16
#define SEQ 1025
#define BATCH 2
#define NH2 32
#define KSCALE (1.0f/48.0f)
#define EPS_RMS 1.1920929e-07f
#define EPS_HEAD 1e-05f
#define LAMBDA_INIT 0.2f
#define R_TOT (BATCH*SEQ)

typedef __attribute__((ext_vector_type(8))) short bf16x8;
typedef __attribute__((ext_vector_type(4))) float f32x4;
typedef __attribute__((ext_vector_type(4))) int  i32x4;

static __device__ __forceinline__ unsigned short f2bf(float x) {
    unsigned int u = __float_as_uint(x);
    unsigned int r = (u + 0x7fffu + ((u >> 16) & 1u)) >> 16;
    return (unsigned short)r;
}
static __device__ __forceinline__ float bf2f(unsigned short h) {
    return __uint_as_float(((unsigned int)h) << 16);
}
static __device__ __forceinline__ void split3(float v, unsigned short& h,
                                              unsigned short& m, unsigned short& l) {
    h = f2bf(v); float r1 = v - bf2f(h);
    m = f2bf(r1); float r2 = r1 - bf2f(m);
    l = f2bf(r2);
}
static __device__ __forceinline__ f32x4 MFMA(bf16x8 a, bf16x8 b, f32x4 c) {
    return __builtin_amdgcn_mfma_f32_16x16x32_bf16(a, b, c, 0, 0, 0);
}

// ---------------------------------------------------------------------------
// ONE conversion kernel: x 3-split + 4 weights 3-split-transpose + Wo 1-plane.
// Block ranges: [0,2050) x | then Wkvd 288 | Wqd 384 | Wkvu 512 | Wqu 576 | Wo 1024
// ---------------------------------------------------------------------------
__global__ __launch_bounds__(256) void conv_all(
    const float* __restrict__ x, const float* __restrict__ Wkvd,
    const float* __restrict__ Wqd, const float* __restrict__ Wkvu,
    const float* __restrict__ Wqu, const float* __restrict__ Wo,
    unsigned short* __restrict__ xh, unsigned short* __restrict__ xm,
    unsigned short* __restrict__ xl,
    unsigned short* __restrict__ Wdh, unsigned short* __restrict__ Wdm,
    unsigned short* __restrict__ Wdl,
    unsigned short* __restrict__ Wuh, unsigned short* __restrict__ Wum,
    unsigned short* __restrict__ Wul,
    unsigned short* __restrict__ Wqh, unsigned short* __restrict__ Wqm,
    unsigned short* __restrict__ Wql,
    unsigned short* __restrict__ Wo1)
{
    __shared__ float tile[32][33];
    int bid = blockIdx.x, tid = threadIdx.x;
    if (bid < 2050) {
        int i = bid * 1024 + tid * 4;
        f32x4 v = *(const f32x4*)(x + i);
#pragma unroll
        for (int j = 0; j < 4; ++j) {
            unsigned short h, m, l;
            split3(v[j], h, m, l);
            xh[i + j] = h; xm[i + j] = m; xl[i + j] = l;
        }
        return;
    }
    bid -= 2050;
    const float* W; unsigned short *Th, *Tm, *Tl; int K, N, gx;
    if (bid < 288)              { W = Wkvd; Th = Wdh; Tm = Wdm; Tl = Wdl; K = 1024; N = 288;  gx = 9;  }
    else if ((bid -= 288) < 384){ W = Wqd;  Th = Wdh + (size_t)288*1024; Tm = Wdm + (size_t)288*1024;
                                  Tl = Wdl + (size_t)288*1024; K = 1024; N = 384; gx = 12; }
    else if ((bid -= 384) < 512){ W = Wkvu; Th = Wuh; Tm = Wum; Tl = Wul; K = 256;  N = 2048; gx = 64; }
    else if ((bid -= 512) < 576){ W = Wqu;  Th = Wqh; Tm = Wqm; Tl = Wql; K = 384;  N = 1536; gx = 48; }
    else { bid -= 576;            W = Wo;   Th = Wo1; Tm = nullptr; Tl = nullptr; K = 1024; N = 1024; gx = 32; }

    int n0 = (bid % gx) * 32, k0 = (bid / gx) * 32;
    int tx = tid & 31, ty = tid >> 5;
    for (int kk = ty; kk < 32; kk += 8)
        tile[kk][tx] = W[(size_t)(k0 + kk) * N + n0 + tx];
    __syncthreads();
    for (int nn = ty; nn < 32; nn += 8) {
        int n = n0 + nn, k = k0 + tx;
        float v = tile[tx][nn];
        if (Tm) {
            unsigned short h, m, l;
            split3(v, h, m, l);
            Th[(size_t)n * K + k] = h;
            Tm[(size_t)n * K + k] = m;
            Tl[(size_t)n * K + k] = l;
        } else {
            Th[(size_t)n * K + k] = f2bf(v);
        }
    }
}

// ---------------------------------------------------------------------------
// 3-way split MFMA GEMM body, frag-ordered LDS (conflict-free b128 r/w).
// LDS per operand: 3 planes x 4096 shorts (128 rows x 32 k).
// epi: 0 plain fp32 C | 1 kv-up scatter | 2 q-up rope scatter
// ---------------------------------------------------------------------------
__device__ __forceinline__ void gemm3_body(
    unsigned short* LA, unsigned short* LB,
    const unsigned short* __restrict__ Ah, const unsigned short* __restrict__ Am,
    const unsigned short* __restrict__ Al,
    const unsigned short* __restrict__ Bh, const unsigned short* __restrict__ Bm,
    const unsigned short* __restrict__ Bl,
    float* __restrict__ C,
    unsigned short* __restrict__ D0, unsigned short* __restrict__ D1,
    unsigned short* __restrict__ D2, unsigned short* __restrict__ D3,
    const float* __restrict__ fcos, const float* __restrict__ fsin,
    int M, int N, int K, int epi, int bm, int bn)
{
    int tid = threadIdx.x;
    int wid = tid >> 6, lane = tid & 63;
    int la = lane & 15, lb = lane >> 4;
    int wr = (wid >> 1) * 64, wc = (wid & 1) * 64;
    int wr4 = wr >> 4, wc4 = wc >> 4;

    const unsigned short* APl[3] = {Ah, Am, Al};
    const unsigned short* BPl[3] = {Bh, Bm, Bl};

    f32x4 acc[4][4];
#pragma unroll
    for (int m = 0; m < 4; ++m)
#pragma unroll
        for (int n = 0; n < 4; ++n) acc[m][n] = (f32x4){0.f, 0.f, 0.f, 0.f};

    auto LDF = [&](bf16x8* dst, const unsigned short* Lb, int p, int rb) {
#pragma unroll
        for (int q = 0; q < 4; ++q)
            dst[q] = *(const bf16x8*)&Lb[p * 4096 + ((rb + q) * 64 + lane) * 8];
    };
    auto MM = [&](bf16x8* av, bf16x8* bv) {
#pragma unroll
        for (int m = 0; m < 4; ++m)
#pragma unroll
            for (int n = 0; n < 4; ++n)
                acc[m][n] = MFMA(av[m], bv[n], acc[m][n]);
    };

    for (int k0 = 0; k0 < K; k0 += 32) {
        __syncthreads();
#pragma unroll
        for (int p = 0; p < 3; ++p) {
#pragma unroll
            for (int it = 0; it < 2; ++it) {
                int k2 = tid + it * 256;
                int g = k2 >> 6, pos = k2 & 63;
                int row = (g << 4) + (pos & 15);
                int kc = (pos >> 4) * 8;
                i32x4 v = {0, 0, 0, 0}, w = {0, 0, 0, 0};
                int gr = bm + row;
                if (gr < M) v = *(const i32x4*)(APl[p] + (size_t)gr * K + k0 + kc);
                *(i32x4*)&LA[p * 4096 + k2 * 8] = v;
                int gn = bn + row;
                if (gn < N) w = *(const i32x4*)(BPl[p] + (size_t)gn * K + k0 + kc);
                *(i32x4*)&LB[p * 4096 + k2 * 8] = w;
            }
        }
        __syncthreads();
        bf16x8 av[4], bv0[4], bv1[4], bvt[4];
        LDF(av, LA, 0, wr4); LDF(bv0, LB, 0, wc4);
        LDF(bv1, LB, 1, wc4); LDF(bvt, LB, 2, wc4);
        __builtin_amdgcn_s_setprio(1);
        MM(av, bv0); MM(av, bv1); MM(av, bvt);   // hh hm hl
        __builtin_amdgcn_s_setprio(0);
        LDF(bvt, LA, 1, wr4);
        __builtin_amdgcn_s_setprio(1);
        MM(bvt, bv0); MM(bvt, bv1);              // mh mm
        __builtin_amdgcn_s_setprio(0);
        LDF(bvt, LA, 2, wr4);
        __builtin_amdgcn_s_setprio(1);
        MM(bvt, bv0);                            // lh
        __builtin_amdgcn_s_setprio(0);
    }

#pragma unroll
    for (int m = 0; m < 4; ++m)
#pragma unroll
        for (int n = 0; n < 4; ++n) {
            int gc = bn + wc + n * 16 + la;
#pragma unroll
            for (int r = 0; r < 4; ++r) {
                int gr = bm + wr + m * 16 + lb * 4 + r;
                float v = acc[m][n][r];
                if (epi == 0) {
                    if (gr < M && gc < N) C[(size_t)gr * N + gc] = v;
                } else if (epi == 1) {
                    if (gr < M) {
                        int b = gr / SEQ, s = gr - b * SEQ;
                        int h2 = gc >> 7, rem = gc & 127;
                        if (rem < 64) {
                            int H = 2 * h2 + (rem >> 5), d = rem & 31;
                            size_t idx = (((size_t)b * NH2 + H) * SEQ + s) * 48 + d;
                            unsigned short hh, mm2, ll;
                            split3(v, hh, mm2, ll);
                            D0[idx] = hh; D1[idx] = mm2; D2[idx] = ll;
                        } else {
                            D3[(((size_t)b * NHEAD + h2) * SEQ + s) * 64 + (rem - 64)] = f2bf(v);
                        }
                    }
                } else {
                    float pv = __shfl_xor(v, 1);   // before any guard
                    if (gr < M) {
                        int b = gr / SEQ, s = gr - b * SEQ;
                        int h2 = gc / 96, rem = gc - h2 * 96;
                        int H, d; float outv;
                        if (rem < 64) {
                            H = 2 * h2 + (rem >> 5); d = rem & 31; outv = v;
                        } else {
                            int dd = rem - 64;
                            int e = dd >> 4, j = (dd & 15) >> 1;
                            H = 2 * h2 + e; d = 32 + (dd & 15);
                            if (s != 0) {
                                int p = (s - 1) & 255;
                                float cc = fcos[p * 8 + j], sn = fsin[p * 8 + j];
                                outv = ((la & 1) == 0) ? (v * cc - pv * sn)
                                                       : (pv * sn + v * cc);
                            } else outv = v;
                        }
                        outv *= KSCALE;
                        size_t idx = (((size_t)b * NH2 + H) * SEQ + s) * 48 + d;
                        unsigned short hh, mm2, ll;
                        split3(outv, hh, mm2, ll);
                        D0[idx] = hh; D1[idx] = mm2; D2[idx] = ll;
                    }
                }
            }
        }
}

__global__ __launch_bounds__(256) void gemm_down(
    const unsigned short* __restrict__ Ah, const unsigned short* __restrict__ Am,
    const unsigned short* __restrict__ Al,
    const unsigned short* __restrict__ Bh, const unsigned short* __restrict__ Bm,
    const unsigned short* __restrict__ Bl, float* __restrict__ C)
{
    __shared__ __align__(16) unsigned short LA[3 * 4096];
    __shared__ __align__(16) unsigned short LB[3 * 4096];
    gemm3_body(LA, LB, Ah, Am, Al, Bh, Bm, Bl, C,
               nullptr, nullptr, nullptr, nullptr, nullptr, nullptr,
               R_TOT, 672, 1024, 0, blockIdx.y * 128, blockIdx.x * 128);
}

// merged kv-up (bx<16) + q-up (bx>=16)
__global__ __launch_bounds__(256) void gemm_up(
    const unsigned short* __restrict__ cnh, const unsigned short* __restrict__ cnm,
    const unsigned short* __restrict__ cnl,
    const unsigned short* __restrict__ Wuh, const unsigned short* __restrict__ Wum,
    const unsigned short* __restrict__ Wul,
    const unsigned short* __restrict__ qnh, const unsigned short* __restrict__ qnm,
    const unsigned short* __restrict__ qnl,
    const unsigned short* __restrict__ Wqh, const unsigned short* __restrict__ Wqm,
    const unsigned short* __restrict__ Wql,
    unsigned short* __restrict__ Kah, unsigned short* __restrict__ Kam,
    unsigned short* __restrict__ Kal, unsigned short* __restrict__ Va,
    unsigned short* __restrict__ Qah, unsigned short* __restrict__ Qam,
    unsigned short* __restrict__ Qal,
    const float* __restrict__ fcos, const float* __restrict__ fsin)
{
    __shared__ __align__(16) unsigned short LA[3 * 4096];
    __shared__ __align__(16) unsigned short LB[3 * 4096];
    bool isq = (blockIdx.x >= 16);
    if (!isq)
        gemm3_body(LA, LB, cnh, cnm, cnl, Wuh, Wum, Wul, nullptr,
                   Kah, Kam, Kal, Va, nullptr, nullptr,
                   R_TOT, 2048, 256, 1, blockIdx.y * 128, blockIdx.x * 128);
    else
        gemm3_body(LA, LB, qnh, qnm, qnl, Wqh, Wqm, Wql, nullptr,
                   Qah, Qam, Qal, nullptr, fcos, fsin,
                   R_TOT, 1536, 384, 2, blockIdx.y * 128, (blockIdx.x - 16) * 128);
}

// ---------------------------------------------------------------------------
// 1-plane bf16 GEMM (out-proj), frag-ordered LDS.
// ---------------------------------------------------------------------------
__global__ __launch_bounds__(256) void gemm_out(
    const unsigned short* __restrict__ Ah, const unsigned short* __restrict__ Bh,
    float* __restrict__ C, int M, int N, int K)
{
    __shared__ __align__(16) unsigned short As[4096];
    __shared__ __align__(16) unsigned short Bs[4096];
    int tid = threadIdx.x;
    int wid = tid >> 6, lane = tid & 63;
    int la = lane & 15, lb = lane >> 4;
    int bm = blockIdx.y * 128, bn = blockIdx.x * 128;
    int wr = (wid >> 1) * 64, wc = (wid & 1) * 64;
    int wr4 = wr >> 4, wc4 = wc >> 4;
    f32x4 acc[4][4];
#pragma unroll
    for (int m = 0; m < 4; ++m)
#pragma unroll
        for (int n = 0; n < 4; ++n) acc[m][n] = (f32x4){0.f, 0.f, 0.f, 0.f};
    for (int k0 = 0; k0 < K; k0 += 32) {
        __syncthreads();
#pragma unroll
        for (int it = 0; it < 2; ++it) {
            int k2 = tid + it * 256;
            int g = k2 >> 6, pos = k2 & 63;
            int row = (g << 4) + (pos & 15);
            int kc = (pos >> 4) * 8;
            i32x4 v = {0, 0, 0, 0}, w = {0, 0, 0, 0};
            int gr = bm + row;
            if (gr < M) v = *(const i32x4*)(Ah + (size_t)gr * K + k0 + kc);
            *(i32x4*)&As[k2 * 8] = v;
            int gn = bn + row;
            if (gn < N) w = *(const i32x4*)(Bh + (size_t)gn * K + k0 + kc);
            *(i32x4*)&Bs[k2 * 8] = w;
        }
        __syncthreads();
        bf16x8 a_[4], b_[4];
#pragma unroll
        for (int m = 0; m < 4; ++m) a_[m] = *(const bf16x8*)&As[((wr4 + m) * 64 + lane) * 8];
#pragma unroll
        for (int n = 0; n < 4; ++n) b_[n] = *(const bf16x8*)&Bs[((wc4 + n) * 64 + lane) * 8];
        __builtin_amdgcn_s_setprio(1);
#pragma unroll
        for (int m = 0; m < 4; ++m)
#pragma unroll
            for (int n = 0; n < 4; ++n) acc[m][n] = MFMA(a_[m], b_[n], acc[m][n]);
        __builtin_amdgcn_s_setprio(0);
    }
#pragma unroll
    for (int m = 0; m < 4; ++m)
#pragma unroll
        for (int n = 0; n < 4; ++n) {
            int gc = bn + wc + n * 16 + la;
            if (gc >= N) continue;
#pragma unroll
            for (int r = 0; r < 4; ++r) {
                int gr = bm + wr + m * 16 + lb * 4 + r;
                if (gr < M) C[(size_t)gr * N + gc] = acc[m][n][r];
            }
        }
}

// ---------------------------------------------------------------------------
// RMS-norm both streams + write K-rope dims (3-plane) directly.
// ckvqd: [R][672] fp32 (0..255 ckv | 256..287 rope | 288..671 qd)
// ---------------------------------------------------------------------------
__global__ __launch_bounds__(256) void k_rmsrope3(
    const float* __restrict__ ckvqd,
    unsigned short* __restrict__ cnh, unsigned short* __restrict__ cnm,
    unsigned short* __restrict__ cnl,
    unsigned short* __restrict__ qnh, unsigned short* __restrict__ qnm,
    unsigned short* __restrict__ qnl,
    unsigned short* __restrict__ Kah, unsigned short* __restrict__ Kam,
    unsigned short* __restrict__ Kal,
    const float* __restrict__ gkv, const float* __restrict__ gq,
    const float* __restrict__ fcos, const float* __restrict__ fsin)
{
    __shared__ float red[256];
    __shared__ float rot[32];
    int row = blockIdx.x, tid = threadIdx.x;
    int b = row / SEQ, s = row - b * SEQ;
    const float* cp = ckvqd + (size_t)row * 672;
    float c0 = cp[tid];
    float q0 = cp[288 + tid];
    float q1 = (tid < 128) ? cp[544 + tid] : 0.f;

    red[tid] = c0 * c0;
    __syncthreads();
    for (int o = 128; o; o >>= 1) { if (tid < o) red[tid] += red[tid + o]; __syncthreads(); }
    float inv1 = rsqrtf(red[0] * (1.f / 256.f) + EPS_RMS);
    __syncthreads();
    red[tid] = q0 * q0 + q1 * q1;
    __syncthreads();
    for (int o = 128; o; o >>= 1) { if (tid < o) red[tid] += red[tid + o]; __syncthreads(); }
    float inv2 = rsqrtf(red[0] * (1.f / 384.f) + EPS_RMS);

    unsigned short h, m, l;
    split3(c0 * inv1 * gkv[tid], h, m, l);
    size_t ci = (size_t)row * 256 + tid;
    cnh[ci] = h; cnm[ci] = m; cnl[ci] = l;

    split3(q0 * inv2 * gq[tid], h, m, l);
    size_t qi = (size_t)row * 384 + tid;
    qnh[qi] = h; qnm[qi] = m; qnl[qi] = l;
    if (tid < 128) {
        split3(q1 * inv2 * gq[256 + tid], h, m, l);
        qnh[qi + 256] = h; qnm[qi + 256] = m; qnl[qi + 256] = l;
    }

    if (tid < 16) {
        float r0 = cp[256 + 2 * tid], r1 = cp[256 + 2 * tid + 1];
        float o0, o1;
        if (s == 0) { o0 = r0; o1 = r1; }
        else {
            int p = (s - 1) & 255;
            int j = tid & 7;
            float cc = fcos[p * 8 + j], sn = fsin[p * 8 + j];
            o0 = r0 * cc - r1 * sn;
            o1 = r0 * sn + r1 * cc;
        }
        rot[2 * tid] = o0; rot[2 * tid + 1] = o1;
    }
    __syncthreads();
    for (int t = tid; t < 512; t += 256) {
        int H = t >> 4, dd = t & 15;
        int e = H & 1;
        split3(rot[e * 16 + dd], h, m, l);
        size_t idx = (((size_t)b * NH2 + H) * SEQ + s) * 48 + 32 + dd;
        Kah[idx] = h; Kam[idx] = m; Kal[idx] = l;
    }
}

// ---------------------------------------------------------------------------
// MFMA cog-attention v5: frag-ordered LDS (conflict-free b128), no-max signed
// softmax, reg-prefetch pipeline, setprio around MFMA clusters, XCD swizzle.
// ---------------------------------------------------------------------------
__global__ __launch_bounds__(256, 2) void k_attn5(
    const unsigned short* __restrict__ Qah, const unsigned short* __restrict__ Qam,
    const unsigned short* __restrict__ Qal,
    const unsigned short* __restrict__ Kah, const unsigned short* __restrict__ Kam,
    const unsigned short* __restrict__ Kal,
    const unsigned short* __restrict__ Va, const float* __restrict__ ghead,
    const float* __restrict__ lq1, const float* __restrict__ lk1,
    const float* __restrict__ lq2, const float* __restrict__ lk2,
    unsigned short* __restrict__ attO)
{
    // frag-order: chunk(lane) at [group][lane*8] shorts; group = tile16*2 + khalf
    __shared__ __align__(16) unsigned short KS[6][4096];
    __shared__ __align__(16) unsigned short Vt[4096];
    __shared__ __align__(16) unsigned short Pl[4][1024];

    int bid0 = blockIdx.x;
    int bid = (bid0 & 7) * 68 + (bid0 >> 3);   // bijective XCD swizzle (544=8*68)
    int rt = bid % 17;
    int bh = bid / 17;
    int h = bh & 15, b = bh >> 4;
    int tid = threadIdx.x, wid = tid >> 6, lane = tid & 63;
    int la = lane & 15, lb = lane >> 4;
    int r0 = rt * 64, r0w = r0 + wid * 16;

    float e1 = 0.f, e2 = 0.f;
    for (int i = 0; i < 32; ++i) { e1 = fmaf(lq1[i], lk1[i], e1); e2 = fmaf(lq2[i], lk2[i], e2); }
    float lam = __expf(e1) - __expf(e2) + LAMBDA_INIT;

    int pr[4];
#pragma unroll
    for (int g = 0; g < 4; ++g) {
        int r = r0w + lb * 4 + g;
        pr[g] = (r >= 1 && r < SEQ) ? ((r - 1) & 255) : -1;
    }
    int rA = r0w + la;
    int prA = (rA >= 1 && rA < SEQ) ? ((rA - 1) & 255) : -1;

    int prm = -1;
    for (int i = 0; i < 64; ++i) {
        int r = r0 + i;
        if (r >= 1 && r < SEQ) { int p = (r - 1) & 255; prm = p > prm ? p : prm; }
    }

    const size_t hb1 = ((size_t)(b * NH2 + 2 * h)) * SEQ * 48;
    const size_t hb2 = ((size_t)(b * NH2 + 2 * h + 1)) * SEQ * 48;
    const unsigned short* vp = Va + ((size_t)(b * NHEAD + h)) * SEQ * 64;
    const unsigned short* KP[6] = {Kah + hb1, Kam + hb1, Kal + hb1,
                                   Kah + hb2, Kam + hb2, Kal + hb2};

    int qrow = r0w + la; if (qrow > SEQ - 1) qrow = SEQ - 1;
    bf16x8 zf;
#pragma unroll
    for (int u = 0; u < 8; ++u) zf[u] = 0;
    bf16x8 q1[3][2], q2[3][2];
    {
        const unsigned short* QPl[3] = {Qah, Qam, Qal};
#pragma unroll
        for (int p = 0; p < 3; ++p)
#pragma unroll
            for (int f = 0; f < 2; ++f) {
                if (f == 0 || lb < 2) {
                    q1[p][f] = *(const bf16x8*)(QPl[p] + hb1 + (size_t)qrow * 48 + 32 * f + lb * 8);
                    q2[p][f] = *(const bf16x8*)(QPl[p] + hb2 + (size_t)qrow * 48 + 32 * f + lb * 8);
                } else { q1[p][f] = zf; q2[p][f] = zf; }
            }
    }

    // register prefetch staging (frag-order chunk mapping)
    i32x4 pre[6][2], vv[2];
    auto LOADT = [&](int c0n) {
#pragma unroll
        for (int it = 0; it < 2; ++it) {
            int k = tid + it * 256;
            int g = k >> 6, pos = k & 63;
            int c = ((g >> 1) << 4) + (pos & 15);
            int u = ((g & 1) << 2) + (pos >> 4);
            int gc = c0n + c; if (gc > SEQ - 1) gc = SEQ - 1;
            if (u < 6) {
#pragma unroll
                for (int p = 0; p < 6; ++p)
                    pre[p][it] = *(const i32x4*)(KP[p] + (size_t)gc * 48 + u * 8);
            } else {
#pragma unroll
                for (int p = 0; p < 6; ++p) pre[p][it] = (i32x4){0, 0, 0, 0};
            }
            int cv = k >> 3, uv = k & 7;
            int gv = c0n + cv; if (gv > SEQ - 1) gv = SEQ - 1;
            vv[it] = *(const i32x4*)(vp + (size_t)gv * 64 + uv * 8);
        }
    };
    auto WRITET = [&]() {
#pragma unroll
        for (int it = 0; it < 2; ++it) {
            int k = tid + it * 256;
#pragma unroll
            for (int p = 0; p < 6; ++p)
                *(i32x4*)&KS[p][k * 8] = pre[p][it];    // linear: conflict-free
            int cv = k >> 3, uv = k & 7;
            unsigned short tmp[8];
            *(i32x4*)tmp = vv[it];
            int ko = uv * 8;
#pragma unroll
            for (int j = 0; j < 8; ++j) {
                int d = ko + j;
                int g = ((d >> 4) << 1) + (cv >> 5);
                int pos = (((cv & 31) >> 3) << 4) + (d & 15);
                Vt[g * 512 + pos * 8 + (cv & 7)] = tmp[j];
            }
        }
    };

    f32x4 O1[4], O2[4], VS[4];
#pragma unroll
    for (int nd = 0; nd < 4; ++nd) {
        O1[nd] = (f32x4){0.f, 0.f, 0.f, 0.f};
        O2[nd] = (f32x4){0.f, 0.f, 0.f, 0.f};
        VS[nd] = (f32x4){0.f, 0.f, 0.f, 0.f};
    }
    float dA1[4] = {0.f, 0.f, 0.f, 0.f}, dA2[4] = {0.f, 0.f, 0.f, 0.f};
    float gsA[4] = {0.f, 0.f, 0.f, 0.f};
    f32x4 z = (f32x4){0.f, 0.f, 0.f, 0.f};

    LOADT(0);
    WRITET();
    __syncthreads();

    for (int j = 0; j <= 16; ++j) {
        bool need = (j == 16) ? (prm >= 255)
                              : (((j & 3) == 0) || (prm >= 64 * (j & 3) - 1));
        if (!need) continue;
        int c0 = j * 64;

        int nj = -1;
        for (int t2 = j + 1; t2 <= 16; ++t2) {
            bool nd2 = (t2 == 16) ? (prm >= 255)
                                  : (((t2 & 3) == 0) || (prm >= 64 * (t2 & 3) - 1));
            if (nd2) { nj = t2; break; }
        }
        if (nj >= 0) LOADT(nj * 64);

        // ---- scores S1 / S2 (frag reads linear, conflict-free) ----
        f32x4 s1[4], s2[4];
        __builtin_amdgcn_s_setprio(1);
#pragma unroll
        for (int n = 0; n < 4; ++n) {
            int g0 = (n * 2) * 512 + lane * 8, g1 = (n * 2 + 1) * 512 + lane * 8;
            bf16x8 kh0 = *(const bf16x8*)&KS[0][g0];
            bf16x8 kh1 = *(const bf16x8*)&KS[0][g1];
            bf16x8 km0 = *(const bf16x8*)&KS[1][g0];
            bf16x8 km1 = *(const bf16x8*)&KS[1][g1];
            bf16x8 kl0 = *(const bf16x8*)&KS[2][g0];
            bf16x8 kl1 = *(const bf16x8*)&KS[2][g1];
            f32x4 s = z;
            s = MFMA(q1[0][0], kh0, s); s = MFMA(q1[0][1], kh1, s);
            s = MFMA(q1[0][0], km0, s); s = MFMA(q1[0][1], km1, s);
            s = MFMA(q1[1][0], kh0, s); s = MFMA(q1[1][1], kh1, s);
            s = MFMA(q1[0][0], kl0, s); s = MFMA(q1[0][1], kl1, s);
            s = MFMA(q1[1][0], km0, s); s = MFMA(q1[1][1], km1, s);
            s = MFMA(q1[2][0], kh0, s); s = MFMA(q1[2][1], kh1, s);
            s1[n] = s;
        }
#pragma unroll
        for (int n = 0; n < 4; ++n) {
            int g0 = (n * 2) * 512 + lane * 8, g1 = (n * 2 + 1) * 512 + lane * 8;
            bf16x8 kh0 = *(const bf16x8*)&KS[3][g0];
            bf16x8 kh1 = *(const bf16x8*)&KS[3][g1];
            bf16x8 km0 = *(const bf16x8*)&KS[4][g0];
            bf16x8 km1 = *(const bf16x8*)&KS[4][g1];
            bf16x8 kl0 = *(const bf16x8*)&KS[5][g0];
            bf16x8 kl1 = *(const bf16x8*)&KS[5][g1];
            f32x4 s = z;
            s = MFMA(q2[0][0], kh0, s); s = MFMA(q2[0][1], kh1, s);
            s = MFMA(q2[0][0], km0, s); s = MFMA(q2[0][1], km1, s);
            s = MFMA(q2[1][0], kh0, s); s = MFMA(q2[1][1], kh1, s);
            s = MFMA(q2[0][0], kl0, s); s = MFMA(q2[0][1], kl1, s);
            s = MFMA(q2[1][0], km0, s); s = MFMA(q2[1][1], km1, s);
            s = MFMA(q2[2][0], kh0, s); s = MFMA(q2[2][1], kh1, s);
            s2[n] = s;
        }
        __builtin_amdgcn_s_setprio(0);

        // ---- no-max signed softmax + per-lane sums ----
        unsigned short p1v[4][4], p2v[4][4];
#pragma unroll
        for (int n = 0; n < 4; ++n) {
            int c = c0 + n * 16 + la;
            int cm = (c - 1) & 255;
            bool cin = (c < SEQ);
#pragma unroll
            for (int g = 0; g < 4; ++g) {
                bool al = (c == 0) || (cin && cm <= pr[g]);
                float a = s1[n][g];
                float pa = __expf(fabsf(a));
                float sa = (a > 0.f) ? pa : ((a < 0.f) ? -pa : 0.f);
                if (al) { dA1[g] += pa; gsA[g] += sa; p1v[n][g] = f2bf(sa); }
                else p1v[n][g] = 0;
                float bb = s2[n][g];
                float pb = __expf(fabsf(bb));
                float sb = (bb > 0.f) ? pb : ((bb < 0.f) ? -pb : 0.f);
                if (al) { dA2[g] += pb; p2v[n][g] = f2bf(sb); }
                else p2v[n][g] = 0;
            }
        }

        // ---- P1/P2 -> A-frags via wave-private frag-order LDS ----
#pragma unroll
        for (int n = 0; n < 4; ++n) {
            int pb = (n >> 1) * 512 + (((n & 1) << 1) + (la >> 3)) * 128 + (la & 7);
#pragma unroll
            for (int g = 0; g < 4; ++g)
                Pl[wid][pb + (lb * 4 + g) * 8] = p1v[n][g];
        }
        __asm__ volatile("s_waitcnt lgkmcnt(0)" ::: "memory");
        __builtin_amdgcn_sched_barrier(0);
        bf16x8 p1a0 = *(const bf16x8*)&Pl[wid][lane * 8];
        bf16x8 p1a1 = *(const bf16x8*)&Pl[wid][512 + lane * 8];
#pragma unroll
        for (int n = 0; n < 4; ++n) {
            int pb = (n >> 1) * 512 + (((n & 1) << 1) + (la >> 3)) * 128 + (la & 7);
#pragma unroll
            for (int g = 0; g < 4; ++g)
                Pl[wid][pb + (lb * 4 + g) * 8] = p2v[n][g];
        }
        __asm__ volatile("s_waitcnt lgkmcnt(0)" ::: "memory");
        __builtin_amdgcn_sched_barrier(0);
        bf16x8 p2a0 = *(const bf16x8*)&Pl[wid][lane * 8];
        bf16x8 p2a1 = *(const bf16x8*)&Pl[wid][512 + lane * 8];

        // mask-frags for Vsum
        bf16x8 p0[2];
#pragma unroll
        for (int f = 0; f < 2; ++f)
#pragma unroll
            for (int jb = 0; jb < 8; ++jb) {
                int c = c0 + 32 * f + lb * 8 + jb;
                bool al = (c == 0) || (c < SEQ && ((c - 1) & 255) <= prA);
                p0[f][jb] = al ? (short)0x3F80 : (short)0;
            }

        // ---- PV + VS ----
        __builtin_amdgcn_s_setprio(1);
#pragma unroll
        for (int nd = 0; nd < 4; ++nd) {
            bf16x8 vb0 = *(const bf16x8*)&Vt[(nd * 2) * 512 + lane * 8];
            bf16x8 vb1 = *(const bf16x8*)&Vt[(nd * 2 + 1) * 512 + lane * 8];
            O1[nd] = MFMA(p1a0, vb0, O1[nd]);
            O1[nd] = MFMA(p1a1, vb1, O1[nd]);
            O2[nd] = MFMA(p2a0, vb0, O2[nd]);
            O2[nd] = MFMA(p2a1, vb1, O2[nd]);
            VS[nd] = MFMA(p0[0], vb0, VS[nd]);
            VS[nd] = MFMA(p0[1], vb1, VS[nd]);
        }
        __builtin_amdgcn_s_setprio(0);

        if (nj >= 0) {
            __syncthreads();
            WRITET();
            __syncthreads();
        }
    }

    // ---- final reductions ----
#pragma unroll
    for (int off = 1; off < 16; off <<= 1) {
#pragma unroll
        for (int g = 0; g < 4; ++g) {
            dA1[g] += __shfl_xor(dA1[g], off);
            dA2[g] += __shfl_xor(dA2[g], off);
            gsA[g] += __shfl_xor(gsA[g], off);
        }
    }

    float i1[4], i2g[4], Gl[4];
#pragma unroll
    for (int g = 0; g < 4; ++g) {
        i1[g] = 1.f / dA1[g];
        i2g[g] = 1.f / dA2[g];
        Gl[g] = gsA[g] * i1[g] * (1.f / (float)SEQ) * lam;
    }
    f32x4 outv[4];
#pragma unroll
    for (int nd = 0; nd < 4; ++nd)
#pragma unroll
        for (int g = 0; g < 4; ++g)
            outv[nd][g] = O1[nd][g] * i1[g] - lam * i2g[g] * O2[nd][g] + Gl[g] * VS[nd][g];

    float ssq[4] = {0.f, 0.f, 0.f, 0.f};
#pragma unroll
    for (int nd = 0; nd < 4; ++nd)
#pragma unroll
        for (int g = 0; g < 4; ++g) ssq[g] += outv[nd][g] * outv[nd][g];
#pragma unroll
    for (int off = 1; off < 16; off <<= 1)
#pragma unroll
        for (int g = 0; g < 4; ++g) ssq[g] += __shfl_xor(ssq[g], off);
    float inv[4];
#pragma unroll
    for (int g = 0; g < 4; ++g) inv[g] = rsqrtf(ssq[g] * (1.f / 64.f) + EPS_HEAD);

#pragma unroll
    for (int nd = 0; nd < 4; ++nd) {
        int d = nd * 16 + la;
        float gv = ghead[d];
#pragma unroll
        for (int g = 0; g < 4; ++g) {
            int r = r0w + lb * 4 + g;
            if (r < SEQ)
                attO[(((size_t)b * SEQ + r) * NHEAD + h) * 64 + d] =
                    f2bf(outv[nd][g] * inv[g] * gv);
        }
    }
}

// ---------------------------------------------------------------------------
extern "C" void kernel_launch(void* const* d_in, const int* in_sizes, int n_in,
                              void* d_out, int out_size, void* d_ws, size_t ws_size,
                              hipStream_t stream)
{
    const float* x    = (const float*)d_in[0];
    const float* fcos = (const float*)d_in[2];
    const float* fsin = (const float*)d_in[3];
    const float* Wkvd = (const float*)d_in[4];
    const float* Wqd  = (const float*)d_in[5];
    const float* Wkvu = (const float*)d_in[6];
    const float* Wqu  = (const float*)d_in[7];
    const float* Wo   = (const float*)d_in[8];
    const float* gkv  = (const float*)d_in[9];
    const float* gq   = (const float*)d_in[10];
    const float* gh   = (const float*)d_in[11];
    const float* lq1  = (const float*)d_in[12];
    const float* lk1  = (const float*)d_in[13];
    const float* lq2  = (const float*)d_in[14];
    const float* lk2  = (const float*)d_in[15];
    float* out = (float*)d_out;

    const int R = R_TOT;  // 2050
    char* base = (char*)d_ws;
    size_t off = 0;
    auto alloc = [&](size_t bytes) -> char* {
        char* p = base + off;
        off = (off + bytes + 255) & ~(size_t)255;
        return p;
    };
    const size_t KPL = (size_t)BATCH * NH2 * SEQ * 48 * 2;   // per K/Q plane

    unsigned short* xh = (unsigned short*)alloc((size_t)R * 1024 * 2);
    unsigned short* xm = (unsigned short*)alloc((size_t)R * 1024 * 2);
    unsigned short* xl = (unsigned short*)alloc((size_t)R * 1024 * 2);
    unsigned short* attO = xh;                      // x dead after down-GEMM
    unsigned short* Kah  = xm;                      // KPL fits xm+xl

    float* ckvqd = (float*)alloc((size_t)R * 672 * 4);
    unsigned short* cnh = (unsigned short*)alloc((size_t)R * 256 * 2);
    unsigned short* cnm = (unsigned short*)alloc((size_t)R * 256 * 2);
    unsigned short* cnl = (unsigned short*)alloc((size_t)R * 256 * 2);
    unsigned short* qnh = (unsigned short*)alloc((size_t)R * 384 * 2);
    unsigned short* qnm = (unsigned short*)alloc((size_t)R * 384 * 2);
    unsigned short* qnl = (unsigned short*)alloc((size_t)R * 384 * 2);
    unsigned short* Kam = (unsigned short*)alloc(KPL);
    unsigned short* Kal = (unsigned short*)alloc(KPL);
    unsigned short* Qah = (unsigned short*)alloc(KPL);
    unsigned short* Qam = (unsigned short*)alloc(KPL);
    unsigned short* Qal = (unsigned short*)alloc(KPL);
    unsigned short* Va  = (unsigned short*)alloc((size_t)BATCH * NHEAD * SEQ * 64 * 2);
    unsigned short* Wdh = (unsigned short*)alloc((size_t)672 * 1024 * 2);
    unsigned short* Wdm = (unsigned short*)alloc((size_t)672 * 1024 * 2);
    unsigned short* Wdl = (unsigned short*)alloc((size_t)672 * 1024 * 2);
    unsigned short* Wuh = (unsigned short*)alloc((size_t)2048 * 256 * 2);
    unsigned short* Wum = (unsigned short*)alloc((size_t)2048 * 256 * 2);
    unsigned short* Wul = (unsigned short*)alloc((size_t)2048 * 256 * 2);
    unsigned short* Wqh = (unsigned short*)alloc((size_t)1536 * 384 * 2);
    unsigned short* Wqm = (unsigned short*)alloc((size_t)1536 * 384 * 2);
    unsigned short* Wql = (unsigned short*)alloc((size_t)1536 * 384 * 2);
    unsigned short* Wo1 = (unsigned short*)alloc((size_t)1024 * 1024 * 2);

    dim3 blk(256);
    // 1: all conversions (x + 5 weights) in one launch
    conv_all<<<4834, blk, 0, stream>>>(x, Wkvd, Wqd, Wkvu, Wqu, Wo,
        xh, xm, xl, Wdh, Wdm, Wdl, Wuh, Wum, Wul, Wqh, Wqm, Wql, Wo1);
    // 2: combined down-proj [R][672]
    gemm_down<<<dim3(6, 17), blk, 0, stream>>>(xh, xm, xl, Wdh, Wdm, Wdl, ckvqd);
    // 3: RMS + split + K-rope
    k_rmsrope3<<<R, blk, 0, stream>>>(ckvqd, cnh, cnm, cnl, qnh, qnm, qnl,
                                      Kah, Kam, Kal, gkv, gq, fcos, fsin);
    // 4: merged kv-up + q-up (scatter epilogues)
    gemm_up<<<dim3(28, 17), blk, 0, stream>>>(cnh, cnm, cnl, Wuh, Wum, Wul,
        qnh, qnm, qnl, Wqh, Wqm, Wql, Kah, Kam, Kal, Va, Qah, Qam, Qal, fcos, fsin);
    // 5: attention
    k_attn5<<<BATCH * NHEAD * 17, blk, 0, stream>>>(Qah, Qam, Qal, Kah, Kam, Kal,
        Va, gh, lq1, lk1, lq2, lk2, attO);
    // 6: output projection
    gemm_out<<<dim3(8, 17), blk, 0, stream>>>(attO, Wo1, out, R, 1024, 1024);
}